// Round 3
// baseline (4299.348 us; speedup 1.0000x reference)
//
#include <hip/hip_runtime.h>
#include <hip/hip_cooperative_groups.h>
#include <math.h>

namespace cg = cooperative_groups;

#define BATCH 256
#define LEN   10000
#define C0 64
#define P0 624
#define T1 155
#define P1 77

// ws offsets (in floats)
#define OFF_CONST 0
#define OFF_Y0    160
#define OFF_Y1    2560160
#define OFF_X     12783776
#define OFF_H0    15306912
#define OFF_C0    15437984
#define OFF_H1    15503520
#define OFF_C1    15634592
#define OFF_Z0    15700128
#define OFF_Z1    15831200
#define OFF_TMP   15962272

// ---------------- host-side savgol constants ----------------
static void invert4(const double A[4][4], double inv[4][4]) {
  double M[4][8];
  for (int i = 0; i < 4; ++i)
    for (int j = 0; j < 4; ++j) { M[i][j] = A[i][j]; M[i][j+4] = (i==j) ? 1.0 : 0.0; }
  for (int col = 0; col < 4; ++col) {
    int p = col;
    for (int r = col+1; r < 4; ++r) if (fabs(M[r][col]) > fabs(M[p][col])) p = r;
    if (p != col) for (int j = 0; j < 8; ++j) { double t = M[col][j]; M[col][j] = M[p][j]; M[p][j] = t; }
    double d = M[col][col];
    for (int j = 0; j < 8; ++j) M[col][j] /= d;
    for (int r = 0; r < 4; ++r) if (r != col) {
      double f = M[r][col];
      for (int j = 0; j < 8; ++j) M[r][j] -= f * M[col][j];
    }
  }
  for (int i = 0; i < 4; ++i) for (int j = 0; j < 4; ++j) inv[i][j] = M[i][j+4];
}

static void compute_consts(float* out) {
  {
    double V[11][4], A[4][4], inv[4][4];
    for (int w = 0; w < 11; ++w) { double t = (double)(w-5), pw = 1.0; for (int m = 0; m < 4; ++m) { V[w][m] = pw; pw *= t; } }
    for (int m = 0; m < 4; ++m) for (int n = 0; n < 4; ++n) { double s = 0; for (int w = 0; w < 11; ++w) s += V[w][m]*V[w][n]; A[m][n] = s; }
    invert4(A, inv);
    for (int w = 0; w < 11; ++w) { double s = 0; for (int m = 0; m < 4; ++m) s += inv[0][m]*V[w][m]; out[w] = (float)s; }
  }
  {
    double V[11][4], A[4][4], inv[4][4], pe[4][11];
    for (int w = 0; w < 11; ++w) { double t = (double)w, pw = 1.0; for (int m = 0; m < 4; ++m) { V[w][m] = pw; pw *= t; } }
    for (int m = 0; m < 4; ++m) for (int n = 0; n < 4; ++n) { double s = 0; for (int w = 0; w < 11; ++w) s += V[w][m]*V[w][n]; A[m][n] = s; }
    invert4(A, inv);
    for (int m = 0; m < 4; ++m) for (int w = 0; w < 11; ++w) { double s = 0; for (int n = 0; n < 4; ++n) s += inv[m][n]*V[w][n]; pe[m][w] = s; }
    for (int w = 0; w < 11; ++w) for (int k = 0; k < 5; ++k) {
      double s = 0, pk = 1.0;
      for (int m = 0; m < 4; ++m) { s += pe[m][w]*pk; pk *= (double)k; }
      out[16 + w*5 + k] = (float)s;
    }
    for (int w = 0; w < 11; ++w) for (int k = 0; k < 5; ++k) {
      double tv = (double)(6+k), s = 0, pk = 1.0;
      for (int m = 0; m < 4; ++m) { s += pe[m][w]*pk; pk *= tv; }
      out[80 + w*5 + k] = (float)s;
    }
  }
}

// ---------------- fused savgol + conv0 + relu + pool2 + bn: x -> y1 (256,64,624) ----------------
__global__ __launch_bounds__(256) void k_sgconv0(const float* __restrict__ x,
    const float* __restrict__ Cc,
    const float* __restrict__ w0, const float* __restrict__ cb0,
    const float* __restrict__ bg0, const float* __restrict__ bb0,
    const float* __restrict__ bm0, const float* __restrict__ bv0,
    float* __restrict__ y1) {
  __shared__ float sw[1024];
  __shared__ float s_sc[64], s_off[64], s_cb[64];
  int tid = threadIdx.x;
  for (int i = tid; i < 1024; i += 256) sw[i] = w0[i];
  if (tid < 64) {
    float sc = bg0[tid] * rsqrtf(bv0[tid] + 1e-5f);
    s_sc[tid] = sc;
    s_off[tid] = bb0[tid] - bm0[tid]*sc;
    s_cb[tid] = cb0[tid];
  }
  __syncthreads();
  int b = blockIdx.y;
  int uu = blockIdx.x*256 + tid;
  if (uu >= P0) return;
  const float* xb = x + b*LEN;
  float hC[11];
#pragma unroll
  for (int w = 0; w < 11; ++w) hC[w] = Cc[w];
  float iv[24];
  if (uu == 0) {
    float xx[32];
    const float4* p = reinterpret_cast<const float4*>(xb);
#pragma unroll
    for (int j = 0; j < 8; ++j) { float4 v = p[j]; xx[4*j]=v.x; xx[4*j+1]=v.y; xx[4*j+2]=v.z; xx[4*j+3]=v.w; }
#pragma unroll
    for (int j = 0; j < 24; ++j) {
      float s = 0.f;
      if (j < 5) {
        for (int w = 0; w < 11; ++w) s += xx[w] * Cc[16 + w*5 + j];
      } else {
        for (int w = 0; w < 11; ++w) s += xx[j-5+w] * hC[w];
      }
      iv[j] = s;
    }
  } else {
    float xx[40];
    const float4* p = reinterpret_cast<const float4*>(xb + 16*uu - 8);
#pragma unroll
    for (int j = 0; j < 10; ++j) { float4 v = p[j]; xx[4*j]=v.x; xx[4*j+1]=v.y; xx[4*j+2]=v.z; xx[4*j+3]=v.w; }
#pragma unroll
    for (int j = 0; j < 24; ++j) {
      float s = 0.f;
#pragma unroll
      for (int w = 0; w < 11; ++w) s += xx[j+3+w] * hC[w];
      iv[j] = s;
    }
  }
  int obase = b*(C0*P0) + uu;
  for (int oc = 0; oc < 64; ++oc) {
    float bias = s_cb[oc];
    float s0 = bias, s1 = bias;
#pragma unroll
    for (int k = 0; k < 16; ++k) {
      float wk = sw[oc*16 + k];
      s0 += iv[k]   * wk;
      s1 += iv[k+8] * wk;
    }
    float pm = fmaxf(fmaxf(s0, 0.f), fmaxf(s1, 0.f));
    y1[obase + oc*P0] = pm*s_sc[oc] + s_off[oc];
  }
}

// ---------------- conv1 as im2col GEMM: 64m x 128n tiles, K=512, 620 blocks ----------------
__global__ __launch_bounds__(256) void k_conv1_gemm(const float* __restrict__ y1,
    const float* __restrict__ w1, const float* __restrict__ cb1,
    float* __restrict__ tmp) {
  __shared__ __align__(16) float a_t[32*66];
  __shared__ __align__(16) float w_t[32*132];
  int m0 = blockIdx.x * 64;
  int tid = threadIdx.x;
  int sa_s = tid & 7, sa_r = tid >> 3;
  int un = tid & 31, mq = tid >> 5;
  int ybase[2];
#pragma unroll
  for (int i = 0; i < 2; ++i) {
    int m = m0 + sa_r + 32*i;
    int b = m / 155, t = m - b*155;
    ybase[i] = b*(C0*P0) + 4*t;
  }
  int ci_off = sa_s >> 1, kkq = (sa_s & 1) * 4;
  float4 av[2], wv[4];
  float acc[8][4] = {{0.f}};
  int swzw = sa_s << 2;

#define CONV1_PREFETCH(cidx) do {                                                   \
    int kc = (cidx) * 32;                                                           \
    int ci0 = kc >> 3;                                                              \
    av[0] = *reinterpret_cast<const float4*>(y1 + ybase[0] + (ci0 + ci_off)*P0 + kkq); \
    av[1] = *reinterpret_cast<const float4*>(y1 + ybase[1] + (ci0 + ci_off)*P0 + kkq); \
    _Pragma("unroll")                                                               \
    for (int i = 0; i < 4; ++i)                                                     \
      wv[i] = *reinterpret_cast<const float4*>(w1 + (sa_r + 32*i)*512 + kc + 4*sa_s); \
  } while (0)

  CONV1_PREFETCH(0);
  for (int cidx = 0; cidx < 16; ++cidx) {
    if (cidx) __syncthreads();
#pragma unroll
    for (int i = 0; i < 2; ++i) {
      int col = sa_r + 32*i;
      a_t[(4*sa_s+0)*66 + col] = av[i].x;
      a_t[(4*sa_s+1)*66 + col] = av[i].y;
      a_t[(4*sa_s+2)*66 + col] = av[i].z;
      a_t[(4*sa_s+3)*66 + col] = av[i].w;
    }
#pragma unroll
    for (int i = 0; i < 4; ++i) {
      int colw = (sa_r + 32*i) ^ swzw;
      w_t[(4*sa_s+0)*132 + colw] = wv[i].x;
      w_t[(4*sa_s+1)*132 + colw] = wv[i].y;
      w_t[(4*sa_s+2)*132 + colw] = wv[i].z;
      w_t[(4*sa_s+3)*132 + colw] = wv[i].w;
    }
    __syncthreads();
    if (cidx + 1 < 16) { CONV1_PREFETCH(cidx + 1); }
#pragma unroll
    for (int k = 0; k < 32; ++k) {
      float4 w4 = *reinterpret_cast<const float4*>(&w_t[k*132 + ((4*un) ^ ((k>>2)<<2))]);
      float2 a2[4];
#pragma unroll
      for (int i = 0; i < 4; ++i)
        a2[i] = *reinterpret_cast<const float2*>(&a_t[k*66 + 2*mq + 16*i]);
#pragma unroll
      for (int i = 0; i < 4; ++i) {
        acc[2*i+0][0] += a2[i].x*w4.x; acc[2*i+0][1] += a2[i].x*w4.y;
        acc[2*i+0][2] += a2[i].x*w4.z; acc[2*i+0][3] += a2[i].x*w4.w;
        acc[2*i+1][0] += a2[i].y*w4.x; acc[2*i+1][1] += a2[i].y*w4.y;
        acc[2*i+1][2] += a2[i].y*w4.z; acc[2*i+1][3] += a2[i].y*w4.w;
      }
    }
  }
#undef CONV1_PREFETCH
  float4 bias = *reinterpret_cast<const float4*>(cb1 + 4*un);
#pragma unroll
  for (int i = 0; i < 4; ++i)
#pragma unroll
    for (int jj = 0; jj < 2; ++jj) {
      int m = m0 + 2*mq + 16*i + jj;
      float4 o;
      o.x = acc[2*i+jj][0] + bias.x;
      o.y = acc[2*i+jj][1] + bias.y;
      o.z = acc[2*i+jj][2] + bias.z;
      o.w = acc[2*i+jj][3] + bias.w;
      *reinterpret_cast<float4*>(tmp + m*128 + 4*un) = o;
    }
}

// ---------------- relu + pool2 + bn: tmp -> X (77,256,128) t-major ----------------
__global__ __launch_bounds__(256) void k_pool1(const float* __restrict__ tmp,
    const float* __restrict__ bg1, const float* __restrict__ bb1,
    const float* __restrict__ bm1, const float* __restrict__ bv1,
    float* __restrict__ X) {
  int idx = blockIdx.x*256 + threadIdx.x;
  int u  = idx >> 15;
  int rr = idx & 32767;
  int bb = rr >> 7;
  int oc = rr & 127;
  int base = (bb*155 + 2*u)*128 + oc;
  float t0 = tmp[base], t1 = tmp[base + 128];
  float pm = fmaxf(0.f, fmaxf(t0, t1));
  float sc = bg1[oc] * rsqrtf(bv1[oc] + 1e-5f);
  X[idx] = pm*sc + (bb1[oc] - bm1[oc]*sc);
}

// ---------------- persistent cooperative LSTM (both layers, 78 pipelined steps) ----------------
// 256 blocks x 256 threads, 1 block/CU. Block = (32-batch, 8-unit) tile for BOTH layers.
// LDS: W0cat 48KB + W1cat 64KB persistent (k-major float4-packed) + 4x8KB per-wave a-chunk bufs.
// Waves 0/1: layer0 K=384 k-split; waves 2/3: layer1 K=512 k-split. c-state in registers.
__global__ __launch_bounds__(256, 1) void k_lstm_persist(
    const float* __restrict__ X,
    const float* __restrict__ Wih0, const float* __restrict__ Whh0,
    const float* __restrict__ bih0, const float* __restrict__ bhh0,
    const float* __restrict__ Wih1, const float* __restrict__ Whh1,
    const float* __restrict__ bih1, const float* __restrict__ bhh1,
    float* __restrict__ h0buf, float* __restrict__ h1buf) {
  extern __shared__ float sm[];
  float* w0lds = sm;              // 384*32 = 12288 floats
  float* w1lds = sm + 12288;      // 512*32 = 16384 floats
  float* abuf  = sm + 28672;      // 4 * 2048 floats

  int tid = threadIdx.x;
  int b0 = (blockIdx.x >> 5) * 32;
  int u0 = (blockIdx.x & 31) * 8;

  // ---- load weight tiles once (k-major, float idx = k*32 + ug*4 + g) ----
  for (int e = tid; e < 12288; e += 256) {
    int k = e >> 5; int ug = (e >> 2) & 7; int g = e & 3;
    int row = g*256 + u0 + ug;
    w0lds[e] = (k < 128) ? Wih0[row*128 + k] : Whh0[row*256 + (k - 128)];
  }
  for (int e = tid; e < 16384; e += 256) {
    int k = e >> 5; int ug = (e >> 2) & 7; int g = e & 3;
    int row = g*256 + u0 + ug;
    w1lds[e] = (k < 256) ? Wih1[row*256 + k] : Whh1[row*256 + (k - 256)];
  }
  __syncthreads();

  int wv = tid >> 6;
  int lane = tid & 63;
  int ug = lane & 7, bq = lane >> 3;
  int layer = wv >> 1;
  int half = wv & 1;
  float* aw = abuf + wv*2048;
  int kbeg = (layer == 0) ? (half ? 192 : 0) : (half ? 256 : 0);
  int kend = (layer == 0) ? (half ? 384 : 192) : (half ? 512 : 256);
  const float* wlds = (layer == 0) ? w0lds : w1lds;
  int bl = lane & 31, kq4 = (lane >> 5) * 4;
  int uu = u0 + ug;

  float bsum[4];
#pragma unroll
  for (int g = 0; g < 4; ++g) {
    if (wv == 0)      bsum[g] = bih0[g*256 + uu] + bhh0[g*256 + uu];
    else if (wv == 2) bsum[g] = bih1[g*256 + uu] + bhh1[g*256 + uu];
    else              bsum[g] = 0.f;
  }
  float c_reg[4] = {0.f, 0.f, 0.f, 0.f};

  cg::grid_group grid = cg::this_grid();

  for (int s = 0; s <= 77; ++s) {
    const float* h0r = h0buf + (s & 1) * 65536;
    float*       h0w = h0buf + ((s + 1) & 1) * 65536;
    const float* h1r = h1buf + (s & 1) * 65536;
    float*       h1w = h1buf + ((s + 1) & 1) * 65536;
    bool act = (layer == 0) ? (s < 77) : (s >= 1);
    float acc[4][4] = {{0.f}};
    if (act) {
      int t = layer ? (s - 1) : s;
      for (int c0 = kbeg; c0 < kend; c0 += 64) {
        const float* ap; int astr, aoff;
        if (layer == 0) {
          if (c0 < 128) { ap = X + t*32768; astr = 128; aoff = c0; }
          else          { ap = h0r;         astr = 256; aoff = c0 - 128; }
        } else {
          if (c0 < 256) { ap = h0r;         astr = 256; aoff = c0; }
          else          { ap = h1r;         astr = 256; aoff = c0 - 256; }
        }
        const float* srcp = ap + (b0 + bl)*astr + aoff + kq4;
#pragma unroll
        for (int r = 0; r < 8; ++r) {
          float4 v = *reinterpret_cast<const float4*>(srcp + 8*r);
          int kl = kq4 + 8*r;
          aw[(kl+0)*32 + bl] = v.x;
          aw[(kl+1)*32 + bl] = v.y;
          aw[(kl+2)*32 + bl] = v.z;
          aw[(kl+3)*32 + bl] = v.w;
        }
        __builtin_amdgcn_s_waitcnt(0xc07f);   // lgkmcnt(0): wave-private LDS RAW
        __builtin_amdgcn_wave_barrier();
        const float* wb = wlds + c0*32 + 4*ug;
        const float* ab = aw + 4*bq;
#pragma unroll 8
        for (int k = 0; k < 64; ++k) {
          float4 a4 = *reinterpret_cast<const float4*>(ab + k*32);
          float4 w4 = *reinterpret_cast<const float4*>(wb + k*32);
          acc[0][0] += a4.x*w4.x; acc[0][1] += a4.x*w4.y; acc[0][2] += a4.x*w4.z; acc[0][3] += a4.x*w4.w;
          acc[1][0] += a4.y*w4.x; acc[1][1] += a4.y*w4.y; acc[1][2] += a4.y*w4.z; acc[1][3] += a4.y*w4.w;
          acc[2][0] += a4.z*w4.x; acc[2][1] += a4.z*w4.y; acc[2][2] += a4.z*w4.z; acc[2][3] += a4.z*w4.w;
          acc[3][0] += a4.w*w4.x; acc[3][1] += a4.w*w4.y; acc[3][2] += a4.w*w4.z; acc[3][3] += a4.w*w4.w;
        }
        __builtin_amdgcn_wave_barrier();
      }
    }
    // waves 1,3 export partials (transposed, conflict-free b32)
    if (half == 1) {
      float* scr = abuf + wv*2048;
#pragma unroll
      for (int i = 0; i < 4; ++i)
#pragma unroll
        for (int g = 0; g < 4; ++g)
          scr[(i*4 + g)*64 + lane] = acc[i][g];
    }
    __syncthreads();
    if (half == 0 && act) {
      const float* scr = abuf + (wv + 1)*2048;
      float* hw = (wv == 0) ? h0w : h1w;
#pragma unroll
      for (int i = 0; i < 4; ++i) {
        float gi = acc[i][0] + scr[(i*4+0)*64 + lane] + bsum[0];
        float gf = acc[i][1] + scr[(i*4+1)*64 + lane] + bsum[1];
        float gg = acc[i][2] + scr[(i*4+2)*64 + lane] + bsum[2];
        float go = acc[i][3] + scr[(i*4+3)*64 + lane] + bsum[3];
        float si = 1.f/(1.f + expf(-gi));
        float sf = 1.f/(1.f + expf(-gf));
        float so = 1.f/(1.f + expf(-go));
        float tg = tanhf(gg);
        float cn = sf*c_reg[i] + si*tg;
        c_reg[i] = cn;
        hw[(b0 + 4*bq + i)*256 + uu] = so * tanhf(cn);
      }
    }
    grid.sync();
  }
}

// ---------------- FC: C = act(A @ W^T + b), M=256 ----------------
__global__ __launch_bounds__(256) void k_fc(const float* __restrict__ A,
    const float* __restrict__ W, const float* __restrict__ bias,
    float* __restrict__ Cout, int N, int K, int kshift, int dorelu) {
  __shared__ __align__(16) float sa[16*516];
  int m0 = blockIdx.y * 16;
  int n = blockIdx.x * 16 + (threadIdx.x & 15);
  int m = threadIdx.x >> 4;
  int stride = K + 4;
  for (int i = threadIdx.x; i < 16*K; i += 256) {
    int mm = i >> kshift;
    int kk = i - (mm << kshift);
    sa[mm*stride + kk] = A[(m0+mm)*K + kk];
  }
  __syncthreads();
  const float4* wr = reinterpret_cast<const float4*>(W + n*K);
  const float4* ar = reinterpret_cast<const float4*>(sa + m*stride);
  float acc = 0.f;
  int kq4 = K >> 2;
  for (int kq = 0; kq < kq4; ++kq) {
    float4 wv = wr[kq], av = ar[kq];
    acc += av.x*wv.x + av.y*wv.y + av.z*wv.z + av.w*wv.w;
  }
  acc += bias[n];
  if (dorelu) acc = fmaxf(acc, 0.f);
  Cout[(m0+m)*N + n] = acc;
}

extern "C" void kernel_launch(void* const* d_in, const int* in_sizes, int n_in,
                              void* d_out, int out_size, void* d_ws, size_t ws_size,
                              hipStream_t stream) {
  const float* x       = (const float*)d_in[0];
  const float* conv_w0 = (const float*)d_in[1];
  const float* conv_b0 = (const float*)d_in[2];
  const float* bn_g0   = (const float*)d_in[3];
  const float* bn_b0   = (const float*)d_in[4];
  const float* bn_m0   = (const float*)d_in[5];
  const float* bn_v0   = (const float*)d_in[6];
  const float* conv_w1 = (const float*)d_in[7];
  const float* conv_b1 = (const float*)d_in[8];
  const float* bn_g1   = (const float*)d_in[9];
  const float* bn_b1   = (const float*)d_in[10];
  const float* bn_m1   = (const float*)d_in[11];
  const float* bn_v1   = (const float*)d_in[12];
  const float* Wih0    = (const float*)d_in[13];
  const float* Whh0    = (const float*)d_in[14];
  const float* bih0    = (const float*)d_in[15];
  const float* bhh0    = (const float*)d_in[16];
  const float* Wih1    = (const float*)d_in[17];
  const float* Whh1    = (const float*)d_in[18];
  const float* bih1    = (const float*)d_in[19];
  const float* bhh1    = (const float*)d_in[20];
  const float* fc0_w   = (const float*)d_in[21];
  const float* fc0_b   = (const float*)d_in[22];
  const float* fc1_w   = (const float*)d_in[23];
  const float* fc1_b   = (const float*)d_in[24];
  const float* out_w   = (const float*)d_in[25];
  const float* out_b   = (const float*)d_in[26];
  float* ws = (float*)d_ws;
  float* out = (float*)d_out;

  static float h_consts[160];
  compute_consts(h_consts);
  hipMemcpyAsync(ws + OFF_CONST, h_consts, 160*sizeof(float), hipMemcpyHostToDevice, stream);
  hipMemsetAsync(ws + OFF_H0, 0, 131072*sizeof(float), stream);
  hipMemsetAsync(ws + OFF_H1, 0, 131072*sizeof(float), stream);

  k_sgconv0<<<dim3(3, BATCH), 256, 0, stream>>>(x, ws + OFF_CONST, conv_w0, conv_b0,
                                                bn_g0, bn_b0, bn_m0, bn_v0, ws + OFF_Y1);
  k_conv1_gemm<<<620, 256, 0, stream>>>(ws + OFF_Y1, conv_w1, conv_b1, ws + OFF_TMP);
  k_pool1<<<9856, 256, 0, stream>>>(ws + OFF_TMP, bn_g1, bn_b1, bn_m1, bn_v1, ws + OFF_X);

  // persistent cooperative LSTM (dynamic LDS 147456 B > 64 KB -> opt-in attribute, idempotent)
  hipFuncSetAttribute(reinterpret_cast<const void*>(k_lstm_persist),
                      hipFuncAttributeMaxDynamicSharedMemorySize, 147456);
  const float* Xp = ws + OFF_X;
  float* h0p = ws + OFF_H0;
  float* h1p = ws + OFF_H1;
  void* cargs[] = {(void*)&Xp, (void*)&Wih0, (void*)&Whh0, (void*)&bih0, (void*)&bhh0,
                   (void*)&Wih1, (void*)&Whh1, (void*)&bih1, (void*)&bhh1,
                   (void*)&h0p, (void*)&h1p};
  hipLaunchCooperativeKernel((void*)k_lstm_persist, dim3(256), dim3(256), cargs, 147456, stream);

  k_fc<<<dim3(32, 16), 256, 0, stream>>>(ws + OFF_H1, fc0_w, fc0_b, ws + OFF_Z0, 512, 256, 8, 1);
  k_fc<<<dim3(32, 16), 256, 0, stream>>>(ws + OFF_Z0, fc1_w, fc1_b, ws + OFF_Z1, 512, 512, 9, 1);
  k_fc<<<dim3(16, 16), 256, 0, stream>>>(ws + OFF_Z1, out_w, out_b, out, 256, 512, 9, 0);
}

// Round 4
// 2497.031 us; speedup vs baseline: 1.7218x; 1.7218x over previous
//
#include <hip/hip_runtime.h>
#include <math.h>

#define BATCH 256
#define LEN   10000
#define C0 64
#define P0 624
#define T1 155
#define P1 77

// ws offsets (in floats)
#define OFF_CONST 0
#define OFF_CTR   160           // 1280 ints (2 layers x 8 bg x 80 steps)
#define OFF_Y1    2560160
#define OFF_X     12783776
#define OFF_H0    15306912
#define OFF_H1    15503520
#define OFF_Z0    15700128
#define OFF_Z1    15831200
#define OFF_TMP   15962272

// ---------------- host-side savgol constants ----------------
static void invert4(const double A[4][4], double inv[4][4]) {
  double M[4][8];
  for (int i = 0; i < 4; ++i)
    for (int j = 0; j < 4; ++j) { M[i][j] = A[i][j]; M[i][j+4] = (i==j) ? 1.0 : 0.0; }
  for (int col = 0; col < 4; ++col) {
    int p = col;
    for (int r = col+1; r < 4; ++r) if (fabs(M[r][col]) > fabs(M[p][col])) p = r;
    if (p != col) for (int j = 0; j < 8; ++j) { double t = M[col][j]; M[col][j] = M[p][j]; M[p][j] = t; }
    double d = M[col][col];
    for (int j = 0; j < 8; ++j) M[col][j] /= d;
    for (int r = 0; r < 4; ++r) if (r != col) {
      double f = M[r][col];
      for (int j = 0; j < 8; ++j) M[r][j] -= f * M[col][j];
    }
  }
  for (int i = 0; i < 4; ++i) for (int j = 0; j < 4; ++j) inv[i][j] = M[i][j+4];
}

static void compute_consts(float* out) {
  {
    double V[11][4], A[4][4], inv[4][4];
    for (int w = 0; w < 11; ++w) { double t = (double)(w-5), pw = 1.0; for (int m = 0; m < 4; ++m) { V[w][m] = pw; pw *= t; } }
    for (int m = 0; m < 4; ++m) for (int n = 0; n < 4; ++n) { double s = 0; for (int w = 0; w < 11; ++w) s += V[w][m]*V[w][n]; A[m][n] = s; }
    invert4(A, inv);
    for (int w = 0; w < 11; ++w) { double s = 0; for (int m = 0; m < 4; ++m) s += inv[0][m]*V[w][m]; out[w] = (float)s; }
  }
  {
    double V[11][4], A[4][4], inv[4][4], pe[4][11];
    for (int w = 0; w < 11; ++w) { double t = (double)w, pw = 1.0; for (int m = 0; m < 4; ++m) { V[w][m] = pw; pw *= t; } }
    for (int m = 0; m < 4; ++m) for (int n = 0; n < 4; ++n) { double s = 0; for (int w = 0; w < 11; ++w) s += V[w][m]*V[w][n]; A[m][n] = s; }
    invert4(A, inv);
    for (int m = 0; m < 4; ++m) for (int w = 0; w < 11; ++w) { double s = 0; for (int n = 0; n < 4; ++n) s += inv[m][n]*V[w][n]; pe[m][w] = s; }
    for (int w = 0; w < 11; ++w) for (int k = 0; k < 5; ++k) {
      double s = 0, pk = 1.0;
      for (int m = 0; m < 4; ++m) { s += pe[m][w]*pk; pk *= (double)k; }
      out[16 + w*5 + k] = (float)s;
    }
    for (int w = 0; w < 11; ++w) for (int k = 0; k < 5; ++k) {
      double tv = (double)(6+k), s = 0, pk = 1.0;
      for (int m = 0; m < 4; ++m) { s += pe[m][w]*pk; pk *= tv; }
      out[80 + w*5 + k] = (float)s;
    }
  }
}

// ---------------- fused savgol + conv0 + relu + pool2 + bn ----------------
__global__ __launch_bounds__(256) void k_sgconv0(const float* __restrict__ x,
    const float* __restrict__ Cc,
    const float* __restrict__ w0, const float* __restrict__ cb0,
    const float* __restrict__ bg0, const float* __restrict__ bb0,
    const float* __restrict__ bm0, const float* __restrict__ bv0,
    float* __restrict__ y1) {
  __shared__ float sw[1024];
  __shared__ float s_sc[64], s_off[64], s_cb[64];
  int tid = threadIdx.x;
  for (int i = tid; i < 1024; i += 256) sw[i] = w0[i];
  if (tid < 64) {
    float sc = bg0[tid] * rsqrtf(bv0[tid] + 1e-5f);
    s_sc[tid] = sc;
    s_off[tid] = bb0[tid] - bm0[tid]*sc;
    s_cb[tid] = cb0[tid];
  }
  __syncthreads();
  int b = blockIdx.y;
  int uu = blockIdx.x*256 + tid;
  if (uu >= P0) return;
  const float* xb = x + b*LEN;
  float hC[11];
#pragma unroll
  for (int w = 0; w < 11; ++w) hC[w] = Cc[w];
  float iv[24];
  if (uu == 0) {
    float xx[32];
    const float4* p = reinterpret_cast<const float4*>(xb);
#pragma unroll
    for (int j = 0; j < 8; ++j) { float4 v = p[j]; xx[4*j]=v.x; xx[4*j+1]=v.y; xx[4*j+2]=v.z; xx[4*j+3]=v.w; }
#pragma unroll
    for (int j = 0; j < 24; ++j) {
      float s = 0.f;
      if (j < 5) {
        for (int w = 0; w < 11; ++w) s += xx[w] * Cc[16 + w*5 + j];
      } else {
        for (int w = 0; w < 11; ++w) s += xx[j-5+w] * hC[w];
      }
      iv[j] = s;
    }
  } else {
    float xx[40];
    const float4* p = reinterpret_cast<const float4*>(xb + 16*uu - 8);
#pragma unroll
    for (int j = 0; j < 10; ++j) { float4 v = p[j]; xx[4*j]=v.x; xx[4*j+1]=v.y; xx[4*j+2]=v.z; xx[4*j+3]=v.w; }
#pragma unroll
    for (int j = 0; j < 24; ++j) {
      float s = 0.f;
#pragma unroll
      for (int w = 0; w < 11; ++w) s += xx[j+3+w] * hC[w];
      iv[j] = s;
    }
  }
  int obase = b*(C0*P0) + uu;
  for (int oc = 0; oc < 64; ++oc) {
    float bias = s_cb[oc];
    float s0 = bias, s1 = bias;
#pragma unroll
    for (int k = 0; k < 16; ++k) {
      float wk = sw[oc*16 + k];
      s0 += iv[k]   * wk;
      s1 += iv[k+8] * wk;
    }
    float pm = fmaxf(fmaxf(s0, 0.f), fmaxf(s1, 0.f));
    y1[obase + oc*P0] = pm*s_sc[oc] + s_off[oc];
  }
}

// ---------------- conv1 as im2col GEMM ----------------
__global__ __launch_bounds__(256) void k_conv1_gemm(const float* __restrict__ y1,
    const float* __restrict__ w1, const float* __restrict__ cb1,
    float* __restrict__ tmp) {
  __shared__ __align__(16) float a_t[32*66];
  __shared__ __align__(16) float w_t[32*132];
  int m0 = blockIdx.x * 64;
  int tid = threadIdx.x;
  int sa_s = tid & 7, sa_r = tid >> 3;
  int un = tid & 31, mq = tid >> 5;
  int ybase[2];
#pragma unroll
  for (int i = 0; i < 2; ++i) {
    int m = m0 + sa_r + 32*i;
    int b = m / 155, t = m - b*155;
    ybase[i] = b*(C0*P0) + 4*t;
  }
  int ci_off = sa_s >> 1, kkq = (sa_s & 1) * 4;
  float4 av[2], wv[4];
  float acc[8][4] = {{0.f}};
  int swzw = sa_s << 2;

#define CONV1_PREFETCH(cidx) do {                                                   \
    int kc = (cidx) * 32;                                                           \
    int ci0 = kc >> 3;                                                              \
    av[0] = *reinterpret_cast<const float4*>(y1 + ybase[0] + (ci0 + ci_off)*P0 + kkq); \
    av[1] = *reinterpret_cast<const float4*>(y1 + ybase[1] + (ci0 + ci_off)*P0 + kkq); \
    _Pragma("unroll")                                                               \
    for (int i = 0; i < 4; ++i)                                                     \
      wv[i] = *reinterpret_cast<const float4*>(w1 + (sa_r + 32*i)*512 + kc + 4*sa_s); \
  } while (0)

  CONV1_PREFETCH(0);
  for (int cidx = 0; cidx < 16; ++cidx) {
    if (cidx) __syncthreads();
#pragma unroll
    for (int i = 0; i < 2; ++i) {
      int col = sa_r + 32*i;
      a_t[(4*sa_s+0)*66 + col] = av[i].x;
      a_t[(4*sa_s+1)*66 + col] = av[i].y;
      a_t[(4*sa_s+2)*66 + col] = av[i].z;
      a_t[(4*sa_s+3)*66 + col] = av[i].w;
    }
#pragma unroll
    for (int i = 0; i < 4; ++i) {
      int colw = (sa_r + 32*i) ^ swzw;
      w_t[(4*sa_s+0)*132 + colw] = wv[i].x;
      w_t[(4*sa_s+1)*132 + colw] = wv[i].y;
      w_t[(4*sa_s+2)*132 + colw] = wv[i].z;
      w_t[(4*sa_s+3)*132 + colw] = wv[i].w;
    }
    __syncthreads();
    if (cidx + 1 < 16) { CONV1_PREFETCH(cidx + 1); }
#pragma unroll
    for (int k = 0; k < 32; ++k) {
      float4 w4 = *reinterpret_cast<const float4*>(&w_t[k*132 + ((4*un) ^ ((k>>2)<<2))]);
      float2 a2[4];
#pragma unroll
      for (int i = 0; i < 4; ++i)
        a2[i] = *reinterpret_cast<const float2*>(&a_t[k*66 + 2*mq + 16*i]);
#pragma unroll
      for (int i = 0; i < 4; ++i) {
        acc[2*i+0][0] += a2[i].x*w4.x; acc[2*i+0][1] += a2[i].x*w4.y;
        acc[2*i+0][2] += a2[i].x*w4.z; acc[2*i+0][3] += a2[i].x*w4.w;
        acc[2*i+1][0] += a2[i].y*w4.x; acc[2*i+1][1] += a2[i].y*w4.y;
        acc[2*i+1][2] += a2[i].y*w4.z; acc[2*i+1][3] += a2[i].y*w4.w;
      }
    }
  }
#undef CONV1_PREFETCH
  float4 bias = *reinterpret_cast<const float4*>(cb1 + 4*un);
#pragma unroll
  for (int i = 0; i < 4; ++i)
#pragma unroll
    for (int jj = 0; jj < 2; ++jj) {
      int m = m0 + 2*mq + 16*i + jj;
      float4 o;
      o.x = acc[2*i+jj][0] + bias.x;
      o.y = acc[2*i+jj][1] + bias.y;
      o.z = acc[2*i+jj][2] + bias.z;
      o.w = acc[2*i+jj][3] + bias.w;
      *reinterpret_cast<float4*>(tmp + m*128 + 4*un) = o;
    }
}

// ---------------- relu + pool2 + bn: tmp -> X (77,256,128) ----------------
__global__ __launch_bounds__(256) void k_pool1(const float* __restrict__ tmp,
    const float* __restrict__ bg1, const float* __restrict__ bb1,
    const float* __restrict__ bm1, const float* __restrict__ bv1,
    float* __restrict__ X) {
  int idx = blockIdx.x*256 + threadIdx.x;
  int u  = idx >> 15;
  int rr = idx & 32767;
  int bb = rr >> 7;
  int oc = rr & 127;
  int base = (bb*155 + 2*u)*128 + oc;
  float t0 = tmp[base], t1 = tmp[base + 128];
  float pm = fmaxf(0.f, fmaxf(t0, t1));
  float sc = bg1[oc] * rsqrtf(bv1[oc] + 1e-5f);
  X[idx] = pm*sc + (bb1[oc] - bm1[oc]*sc);
}

// ---------------- persistent LSTM with dependency-scoped counters ----------------
// 512 blocks x 128 threads (2/CU). Block = (layer = blockIdx&1, bg = batch/32, ut = units/8).
// Weights LDS-resident; 2-wave k-split; h traffic via agent-scope (sc1) atomics (L2 bypass);
// per-(layer,bg,step) arrival counters instead of grid.sync. c-state in registers.
__global__ __launch_bounds__(128) void k_lstm_persist(
    const float* __restrict__ X,
    const float* __restrict__ Wih0, const float* __restrict__ Whh0,
    const float* __restrict__ bih0, const float* __restrict__ bhh0,
    const float* __restrict__ Wih1, const float* __restrict__ Whh1,
    const float* __restrict__ bih1, const float* __restrict__ bhh1,
    float* __restrict__ h0buf, float* __restrict__ h1buf,
    int* __restrict__ ctr) {
  extern __shared__ float sm[];
  float* wlds = sm;                       // up to 512*32 = 16384 floats
  int tid = threadIdx.x;
  int wv = tid >> 6, lane = tid & 63;
  float* aw   = sm + 16384 + wv*1152;     // per-wave 32k x stride-36 A chunk
  float* expb = sm + 16384 + 2*1152;      // 1024-float k-split export

  int layer = blockIdx.x & 1;
  int idx = blockIdx.x >> 1;
  int bg = idx >> 5, ut = idx & 31;
  int b0 = bg*32, u0 = ut*8;
  int K = layer ? 512 : 384;

  // one-time weight staging (k-major: wlds[k*32 + ug*4 + g])
  if (layer == 0) {
    for (int e = tid; e < 384*32; e += 128) {
      int k = e >> 5, ug_ = (e >> 2) & 7, g = e & 3;
      int row = g*256 + u0 + ug_;
      wlds[e] = (k < 128) ? Wih0[row*128 + k] : Whh0[row*256 + k - 128];
    }
  } else {
    for (int e = tid; e < 512*32; e += 128) {
      int k = e >> 5, ug_ = (e >> 2) & 7, g = e & 3;
      int row = g*256 + u0 + ug_;
      wlds[e] = (k < 256) ? Wih1[row*256 + k] : Whh1[row*256 + k - 256];
    }
  }

  int bl = lane & 31, q = lane >> 5;      // staging map
  int ug = lane & 7, bq = lane >> 3;      // compute map
  int uu = u0 + ug;
  float bsum[4] = {0.f, 0.f, 0.f, 0.f};
  if (wv == 0) {
    const float* bi = layer ? bih1 : bih0;
    const float* bh = layer ? bhh1 : bhh0;
#pragma unroll
    for (int g = 0; g < 4; ++g) bsum[g] = bi[g*256 + uu] + bh[g*256 + uu];
  }
  float c_reg[4] = {0.f, 0.f, 0.f, 0.f};
  int kbeg = wv * (K >> 1);
  int nch = K >> 6;                       // chunks of 32 per wave: 6 (L0) / 8 (L1)
  int* c0p = ctr + bg*80;
  int* c1p = ctr + 640 + bg*80;
  __syncthreads();

  for (int s = 0; s < 77; ++s) {
    // dependency waits (relaxed agent loads; sc1 -> coherent, no L2 invalidate)
    {
      int w0t = -1, w1t = -1;
      if (layer == 0) { if (s >= 1) w0t = s-1; if (s >= 2) w1t = s-2; }
      else            { w0t = s;               if (s >= 1) w1t = s-1; }
      int guard = 0;
      for (;;) {
        int ok = 1;
        if (w0t >= 0 && __hip_atomic_load(c0p + w0t, __ATOMIC_RELAXED, __HIP_MEMORY_SCOPE_AGENT) < 32) ok = 0;
        if (ok && w1t >= 0 && __hip_atomic_load(c1p + w1t, __ATOMIC_RELAXED, __HIP_MEMORY_SCOPE_AGENT) < 32) ok = 0;
        if (ok || ++guard > (1 << 22)) break;
        __builtin_amdgcn_s_sleep(1);
      }
    }
    __syncthreads();

    const float* h0r  = h0buf + (s & 1)*65536;        // h0[s-1]
    const float* h0r2 = h0buf + ((s+1) & 1)*65536;    // h0[s]   (layer1 input)
    const float* h1r  = h1buf + (s & 1)*65536;        // h1[s-1]
    float* h0w = h0buf + ((s+1) & 1)*65536;
    float* h1w = h1buf + ((s+1) & 1)*65536;

    float acc[4][4] = {{0.f}};
    float hs[2][16];

#define LOADC(c) do {                                                              \
    int kc = kbeg + (c)*32;                                                        \
    if (layer == 0 && kc < 128) {                                                  \
      const float* ap = X + (size_t)s*32768 + (b0+bl)*128 + kc + q*16;             \
      _Pragma("unroll")                                                            \
      for (int i = 0; i < 4; ++i) {                                                \
        float4 v = *reinterpret_cast<const float4*>(ap + 4*i);                     \
        hs[(c)&1][4*i+0] = v.x; hs[(c)&1][4*i+1] = v.y;                            \
        hs[(c)&1][4*i+2] = v.z; hs[(c)&1][4*i+3] = v.w;                            \
      }                                                                            \
    } else {                                                                       \
      const float* hp; int off;                                                    \
      if (layer == 0)      { hp = h0r;  off = kc - 128; }                          \
      else if (kc < 256)   { hp = h0r2; off = kc; }                                \
      else                 { hp = h1r;  off = kc - 256; }                          \
      const float* ap = hp + (b0+bl)*256 + off + q*16;                             \
      _Pragma("unroll")                                                            \
      for (int i = 0; i < 16; ++i)                                                 \
        hs[(c)&1][i] = __hip_atomic_load(ap + i, __ATOMIC_RELAXED, __HIP_MEMORY_SCOPE_AGENT); \
    }                                                                              \
  } while (0)

    LOADC(0);
    LOADC(1);
#pragma unroll
    for (int c = 0; c < 8; ++c) {
      if (c >= nch) break;
#pragma unroll
      for (int j = 0; j < 16; ++j)
        aw[(q*16 + j)*36 + bl] = hs[c & 1][j];
      if (c + 2 < nch) { LOADC(c + 2); }
#pragma unroll 8
      for (int kl = 0; kl < 32; ++kl) {
        float4 a4 = *reinterpret_cast<const float4*>(&aw[kl*36 + 4*bq]);
        float4 w4 = *reinterpret_cast<const float4*>(&wlds[(kbeg + c*32 + kl)*32 + 4*ug]);
        acc[0][0] += a4.x*w4.x; acc[0][1] += a4.x*w4.y; acc[0][2] += a4.x*w4.z; acc[0][3] += a4.x*w4.w;
        acc[1][0] += a4.y*w4.x; acc[1][1] += a4.y*w4.y; acc[1][2] += a4.y*w4.z; acc[1][3] += a4.y*w4.w;
        acc[2][0] += a4.z*w4.x; acc[2][1] += a4.z*w4.y; acc[2][2] += a4.z*w4.z; acc[2][3] += a4.z*w4.w;
        acc[3][0] += a4.w*w4.x; acc[3][1] += a4.w*w4.y; acc[3][2] += a4.w*w4.z; acc[3][3] += a4.w*w4.w;
      }
    }
#undef LOADC

    if (wv == 1) {
#pragma unroll
      for (int i = 0; i < 4; ++i)
#pragma unroll
        for (int g = 0; g < 4; ++g)
          expb[(i*4 + g)*64 + lane] = acc[i][g];
    }
    __syncthreads();
    if (wv == 0) {
      float* hw = layer ? h1w : h0w;
#pragma unroll
      for (int i = 0; i < 4; ++i) {
        float gi = acc[i][0] + expb[(i*4+0)*64 + lane] + bsum[0];
        float gf = acc[i][1] + expb[(i*4+1)*64 + lane] + bsum[1];
        float gg = acc[i][2] + expb[(i*4+2)*64 + lane] + bsum[2];
        float go = acc[i][3] + expb[(i*4+3)*64 + lane] + bsum[3];
        float si = 1.f/(1.f + expf(-gi));
        float sf = 1.f/(1.f + expf(-gf));
        float so = 1.f/(1.f + expf(-go));
        float tg = tanhf(gg);
        float cn = sf*c_reg[i] + si*tg;
        c_reg[i] = cn;
        float hv = so * tanhf(cn);
        __hip_atomic_store(hw + (b0 + 4*bq + i)*256 + uu, hv,
                           __ATOMIC_RELAXED, __HIP_MEMORY_SCOPE_AGENT);
      }
      __builtin_amdgcn_s_waitcnt(0);
      __asm__ __volatile__("" ::: "memory");
      if (lane == 0) atomicAdd((layer ? c1p : c0p) + s, 1);
    }
  }
}

// ---------------- FC: C = act(A @ W^T + b), M=256 ----------------
__global__ __launch_bounds__(256) void k_fc(const float* __restrict__ A,
    const float* __restrict__ W, const float* __restrict__ bias,
    float* __restrict__ Cout, int N, int K, int kshift, int dorelu) {
  __shared__ __align__(16) float sa[16*516];
  int m0 = blockIdx.y * 16;
  int n = blockIdx.x * 16 + (threadIdx.x & 15);
  int m = threadIdx.x >> 4;
  int stride = K + 4;
  for (int i = threadIdx.x; i < 16*K; i += 256) {
    int mm = i >> kshift;
    int kk = i - (mm << kshift);
    sa[mm*stride + kk] = A[(m0+mm)*K + kk];
  }
  __syncthreads();
  const float4* wr = reinterpret_cast<const float4*>(W + n*K);
  const float4* ar = reinterpret_cast<const float4*>(sa + m*stride);
  float acc = 0.f;
  int kq4 = K >> 2;
  for (int kq = 0; kq < kq4; ++kq) {
    float4 wv = wr[kq], av = ar[kq];
    acc += av.x*wv.x + av.y*wv.y + av.z*wv.z + av.w*wv.w;
  }
  acc += bias[n];
  if (dorelu) acc = fmaxf(acc, 0.f);
  Cout[(m0+m)*N + n] = acc;
}

extern "C" void kernel_launch(void* const* d_in, const int* in_sizes, int n_in,
                              void* d_out, int out_size, void* d_ws, size_t ws_size,
                              hipStream_t stream) {
  const float* x       = (const float*)d_in[0];
  const float* conv_w0 = (const float*)d_in[1];
  const float* conv_b0 = (const float*)d_in[2];
  const float* bn_g0   = (const float*)d_in[3];
  const float* bn_b0   = (const float*)d_in[4];
  const float* bn_m0   = (const float*)d_in[5];
  const float* bn_v0   = (const float*)d_in[6];
  const float* conv_w1 = (const float*)d_in[7];
  const float* conv_b1 = (const float*)d_in[8];
  const float* bn_g1   = (const float*)d_in[9];
  const float* bn_b1   = (const float*)d_in[10];
  const float* bn_m1   = (const float*)d_in[11];
  const float* bn_v1   = (const float*)d_in[12];
  const float* Wih0    = (const float*)d_in[13];
  const float* Whh0    = (const float*)d_in[14];
  const float* bih0    = (const float*)d_in[15];
  const float* bhh0    = (const float*)d_in[16];
  const float* Wih1    = (const float*)d_in[17];
  const float* Whh1    = (const float*)d_in[18];
  const float* bih1    = (const float*)d_in[19];
  const float* bhh1    = (const float*)d_in[20];
  const float* fc0_w   = (const float*)d_in[21];
  const float* fc0_b   = (const float*)d_in[22];
  const float* fc1_w   = (const float*)d_in[23];
  const float* fc1_b   = (const float*)d_in[24];
  const float* out_w   = (const float*)d_in[25];
  const float* out_b   = (const float*)d_in[26];
  float* ws = (float*)d_ws;
  float* out = (float*)d_out;

  static float h_consts[160];
  compute_consts(h_consts);
  hipMemcpyAsync(ws + OFF_CONST, h_consts, 160*sizeof(float), hipMemcpyHostToDevice, stream);
  hipMemsetAsync(ws + OFF_CTR, 0, 1280*sizeof(int), stream);
  hipMemsetAsync(ws + OFF_H0, 0, 131072*sizeof(float), stream);
  hipMemsetAsync(ws + OFF_H1, 0, 131072*sizeof(float), stream);

  k_sgconv0<<<dim3(3, BATCH), 256, 0, stream>>>(x, ws + OFF_CONST, conv_w0, conv_b0,
                                                bn_g0, bn_b0, bn_m0, bn_v0, ws + OFF_Y1);
  k_conv1_gemm<<<620, 256, 0, stream>>>(ws + OFF_Y1, conv_w1, conv_b1, ws + OFF_TMP);
  k_pool1<<<9856, 256, 0, stream>>>(ws + OFF_TMP, bn_g1, bn_b1, bn_m1, bn_v1, ws + OFF_X);

  // persistent LSTM: cooperative launch only for co-residency guarantee (no grid.sync inside)
  hipFuncSetAttribute(reinterpret_cast<const void*>(k_lstm_persist),
                      hipFuncAttributeMaxDynamicSharedMemorySize, 78848);
  const float* Xp = ws + OFF_X;
  float* h0p = ws + OFF_H0;
  float* h1p = ws + OFF_H1;
  int* ctrp = (int*)(ws + OFF_CTR);
  void* cargs[] = {(void*)&Xp, (void*)&Wih0, (void*)&Whh0, (void*)&bih0, (void*)&bhh0,
                   (void*)&Wih1, (void*)&Whh1, (void*)&bih1, (void*)&bhh1,
                   (void*)&h0p, (void*)&h1p, (void*)&ctrp};
  hipLaunchCooperativeKernel((void*)k_lstm_persist, dim3(512), dim3(128), cargs, 78848, stream);

  // final h1[76] lives at parity (76+1)&1 = 1
  k_fc<<<dim3(32, 16), 256, 0, stream>>>(ws + OFF_H1 + 65536, fc0_w, fc0_b, ws + OFF_Z0, 512, 256, 8, 1);
  k_fc<<<dim3(32, 16), 256, 0, stream>>>(ws + OFF_Z0, fc1_w, fc1_b, ws + OFF_Z1, 512, 512, 9, 1);
  k_fc<<<dim3(16, 16), 256, 0, stream>>>(ws + OFF_Z1, out_w, out_b, out, 256, 512, 9, 0);
}

// Round 5
// 1985.275 us; speedup vs baseline: 2.1656x; 1.2578x over previous
//
#include <hip/hip_runtime.h>
#include <math.h>

#define BATCH 256
#define LEN   10000
#define C0 64
#define P0 624
#define T1 155
#define P1 77

// ws offsets (in floats)
#define OFF_CONST 0
#define OFF_CTR   160           // 1280 ints (2 layers x 8 bg x 80 steps)
#define OFF_Y1    2560160
#define OFF_X     12783776
#define OFF_H0    15306912
#define OFF_H1    15503520
#define OFF_Z0    15700128
#define OFF_Z1    15831200
#define OFF_TMP   15962272

// ---------------- host-side savgol constants ----------------
static void invert4(const double A[4][4], double inv[4][4]) {
  double M[4][8];
  for (int i = 0; i < 4; ++i)
    for (int j = 0; j < 4; ++j) { M[i][j] = A[i][j]; M[i][j+4] = (i==j) ? 1.0 : 0.0; }
  for (int col = 0; col < 4; ++col) {
    int p = col;
    for (int r = col+1; r < 4; ++r) if (fabs(M[r][col]) > fabs(M[p][col])) p = r;
    if (p != col) for (int j = 0; j < 8; ++j) { double t = M[col][j]; M[col][j] = M[p][j]; M[p][j] = t; }
    double d = M[col][col];
    for (int j = 0; j < 8; ++j) M[col][j] /= d;
    for (int r = 0; r < 4; ++r) if (r != col) {
      double f = M[r][col];
      for (int j = 0; j < 8; ++j) M[r][j] -= f * M[col][j];
    }
  }
  for (int i = 0; i < 4; ++i) for (int j = 0; j < 4; ++j) inv[i][j] = M[i][j+4];
}

static void compute_consts(float* out) {
  {
    double V[11][4], A[4][4], inv[4][4];
    for (int w = 0; w < 11; ++w) { double t = (double)(w-5), pw = 1.0; for (int m = 0; m < 4; ++m) { V[w][m] = pw; pw *= t; } }
    for (int m = 0; m < 4; ++m) for (int n = 0; n < 4; ++n) { double s = 0; for (int w = 0; w < 11; ++w) s += V[w][m]*V[w][n]; A[m][n] = s; }
    invert4(A, inv);
    for (int w = 0; w < 11; ++w) { double s = 0; for (int m = 0; m < 4; ++m) s += inv[0][m]*V[w][m]; out[w] = (float)s; }
  }
  {
    double V[11][4], A[4][4], inv[4][4], pe[4][11];
    for (int w = 0; w < 11; ++w) { double t = (double)w, pw = 1.0; for (int m = 0; m < 4; ++m) { V[w][m] = pw; pw *= t; } }
    for (int m = 0; m < 4; ++m) for (int n = 0; n < 4; ++n) { double s = 0; for (int w = 0; w < 11; ++w) s += V[w][m]*V[w][n]; A[m][n] = s; }
    invert4(A, inv);
    for (int m = 0; m < 4; ++m) for (int w = 0; w < 11; ++w) { double s = 0; for (int n = 0; n < 4; ++n) s += inv[m][n]*V[w][n]; pe[m][w] = s; }
    for (int w = 0; w < 11; ++w) for (int k = 0; k < 5; ++k) {
      double s = 0, pk = 1.0;
      for (int m = 0; m < 4; ++m) { s += pe[m][w]*pk; pk *= (double)k; }
      out[16 + w*5 + k] = (float)s;
    }
    for (int w = 0; w < 11; ++w) for (int k = 0; k < 5; ++k) {
      double tv = (double)(6+k), s = 0, pk = 1.0;
      for (int m = 0; m < 4; ++m) { s += pe[m][w]*pk; pk *= tv; }
      out[80 + w*5 + k] = (float)s;
    }
  }
}

// ---------------- fused savgol + conv0 + relu + pool2 + bn ----------------
__global__ __launch_bounds__(256) void k_sgconv0(const float* __restrict__ x,
    const float* __restrict__ Cc,
    const float* __restrict__ w0, const float* __restrict__ cb0,
    const float* __restrict__ bg0, const float* __restrict__ bb0,
    const float* __restrict__ bm0, const float* __restrict__ bv0,
    float* __restrict__ y1) {
  __shared__ float sw[1024];
  __shared__ float s_sc[64], s_off[64], s_cb[64];
  int tid = threadIdx.x;
  for (int i = tid; i < 1024; i += 256) sw[i] = w0[i];
  if (tid < 64) {
    float sc = bg0[tid] * rsqrtf(bv0[tid] + 1e-5f);
    s_sc[tid] = sc;
    s_off[tid] = bb0[tid] - bm0[tid]*sc;
    s_cb[tid] = cb0[tid];
  }
  __syncthreads();
  int b = blockIdx.y;
  int uu = blockIdx.x*256 + tid;
  if (uu >= P0) return;
  const float* xb = x + b*LEN;
  float hC[11];
#pragma unroll
  for (int w = 0; w < 11; ++w) hC[w] = Cc[w];
  float iv[24];
  if (uu == 0) {
    float xx[32];
    const float4* p = reinterpret_cast<const float4*>(xb);
#pragma unroll
    for (int j = 0; j < 8; ++j) { float4 v = p[j]; xx[4*j]=v.x; xx[4*j+1]=v.y; xx[4*j+2]=v.z; xx[4*j+3]=v.w; }
#pragma unroll
    for (int j = 0; j < 24; ++j) {
      float s = 0.f;
      if (j < 5) {
        for (int w = 0; w < 11; ++w) s += xx[w] * Cc[16 + w*5 + j];
      } else {
        for (int w = 0; w < 11; ++w) s += xx[j-5+w] * hC[w];
      }
      iv[j] = s;
    }
  } else {
    float xx[40];
    const float4* p = reinterpret_cast<const float4*>(xb + 16*uu - 8);
#pragma unroll
    for (int j = 0; j < 10; ++j) { float4 v = p[j]; xx[4*j]=v.x; xx[4*j+1]=v.y; xx[4*j+2]=v.z; xx[4*j+3]=v.w; }
#pragma unroll
    for (int j = 0; j < 24; ++j) {
      float s = 0.f;
#pragma unroll
      for (int w = 0; w < 11; ++w) s += xx[j+3+w] * hC[w];
      iv[j] = s;
    }
  }
  int obase = b*(C0*P0) + uu;
  for (int oc = 0; oc < 64; ++oc) {
    float bias = s_cb[oc];
    float s0 = bias, s1 = bias;
#pragma unroll
    for (int k = 0; k < 16; ++k) {
      float wk = sw[oc*16 + k];
      s0 += iv[k]   * wk;
      s1 += iv[k+8] * wk;
    }
    float pm = fmaxf(fmaxf(s0, 0.f), fmaxf(s1, 0.f));
    y1[obase + oc*P0] = pm*s_sc[oc] + s_off[oc];
  }
}

// ---------------- conv1 as im2col GEMM ----------------
__global__ __launch_bounds__(256) void k_conv1_gemm(const float* __restrict__ y1,
    const float* __restrict__ w1, const float* __restrict__ cb1,
    float* __restrict__ tmp) {
  __shared__ __align__(16) float a_t[32*66];
  __shared__ __align__(16) float w_t[32*132];
  int m0 = blockIdx.x * 64;
  int tid = threadIdx.x;
  int sa_s = tid & 7, sa_r = tid >> 3;
  int un = tid & 31, mq = tid >> 5;
  int ybase[2];
#pragma unroll
  for (int i = 0; i < 2; ++i) {
    int m = m0 + sa_r + 32*i;
    int b = m / 155, t = m - b*155;
    ybase[i] = b*(C0*P0) + 4*t;
  }
  int ci_off = sa_s >> 1, kkq = (sa_s & 1) * 4;
  float4 av[2], wv[4];
  float acc[8][4] = {{0.f}};
  int swzw = sa_s << 2;

#define CONV1_PREFETCH(cidx) do {                                                   \
    int kc = (cidx) * 32;                                                           \
    int ci0 = kc >> 3;                                                              \
    av[0] = *reinterpret_cast<const float4*>(y1 + ybase[0] + (ci0 + ci_off)*P0 + kkq); \
    av[1] = *reinterpret_cast<const float4*>(y1 + ybase[1] + (ci0 + ci_off)*P0 + kkq); \
    _Pragma("unroll")                                                               \
    for (int i = 0; i < 4; ++i)                                                     \
      wv[i] = *reinterpret_cast<const float4*>(w1 + (sa_r + 32*i)*512 + kc + 4*sa_s); \
  } while (0)

  CONV1_PREFETCH(0);
  for (int cidx = 0; cidx < 16; ++cidx) {
    if (cidx) __syncthreads();
#pragma unroll
    for (int i = 0; i < 2; ++i) {
      int col = sa_r + 32*i;
      a_t[(4*sa_s+0)*66 + col] = av[i].x;
      a_t[(4*sa_s+1)*66 + col] = av[i].y;
      a_t[(4*sa_s+2)*66 + col] = av[i].z;
      a_t[(4*sa_s+3)*66 + col] = av[i].w;
    }
#pragma unroll
    for (int i = 0; i < 4; ++i) {
      int colw = (sa_r + 32*i) ^ swzw;
      w_t[(4*sa_s+0)*132 + colw] = wv[i].x;
      w_t[(4*sa_s+1)*132 + colw] = wv[i].y;
      w_t[(4*sa_s+2)*132 + colw] = wv[i].z;
      w_t[(4*sa_s+3)*132 + colw] = wv[i].w;
    }
    __syncthreads();
    if (cidx + 1 < 16) { CONV1_PREFETCH(cidx + 1); }
#pragma unroll
    for (int k = 0; k < 32; ++k) {
      float4 w4 = *reinterpret_cast<const float4*>(&w_t[k*132 + ((4*un) ^ ((k>>2)<<2))]);
      float2 a2[4];
#pragma unroll
      for (int i = 0; i < 4; ++i)
        a2[i] = *reinterpret_cast<const float2*>(&a_t[k*66 + 2*mq + 16*i]);
#pragma unroll
      for (int i = 0; i < 4; ++i) {
        acc[2*i+0][0] += a2[i].x*w4.x; acc[2*i+0][1] += a2[i].x*w4.y;
        acc[2*i+0][2] += a2[i].x*w4.z; acc[2*i+0][3] += a2[i].x*w4.w;
        acc[2*i+1][0] += a2[i].y*w4.x; acc[2*i+1][1] += a2[i].y*w4.y;
        acc[2*i+1][2] += a2[i].y*w4.z; acc[2*i+1][3] += a2[i].y*w4.w;
      }
    }
  }
#undef CONV1_PREFETCH
  float4 bias = *reinterpret_cast<const float4*>(cb1 + 4*un);
#pragma unroll
  for (int i = 0; i < 4; ++i)
#pragma unroll
    for (int jj = 0; jj < 2; ++jj) {
      int m = m0 + 2*mq + 16*i + jj;
      float4 o;
      o.x = acc[2*i+jj][0] + bias.x;
      o.y = acc[2*i+jj][1] + bias.y;
      o.z = acc[2*i+jj][2] + bias.z;
      o.w = acc[2*i+jj][3] + bias.w;
      *reinterpret_cast<float4*>(tmp + m*128 + 4*un) = o;
    }
}

// ---------------- relu + pool2 + bn: tmp -> X (77,256,128) ----------------
__global__ __launch_bounds__(256) void k_pool1(const float* __restrict__ tmp,
    const float* __restrict__ bg1, const float* __restrict__ bb1,
    const float* __restrict__ bm1, const float* __restrict__ bv1,
    float* __restrict__ X) {
  int idx = blockIdx.x*256 + threadIdx.x;
  int u  = idx >> 15;
  int rr = idx & 32767;
  int bb = rr >> 7;
  int oc = rr & 127;
  int base = (bb*155 + 2*u)*128 + oc;
  float t0 = tmp[base], t1 = tmp[base + 128];
  float pm = fmaxf(0.f, fmaxf(t0, t1));
  float sc = bg1[oc] * rsqrtf(bv1[oc] + 1e-5f);
  X[idx] = pm*sc + (bb1[oc] - bm1[oc]*sc);
}

// ---------------- persistent LSTM with dependency-scoped counters ----------------
// 512 blocks x 128 threads (2/CU). Block = (layer, bg = batch/32, ut = units/8).
// Weights LDS-resident; 2-wave k-split; h via agent-scope (coherent) 8B atomic loads;
// SINGLE-THREAD poll per block with s_sleep backoff (kills L3 poll contention).
__global__ __launch_bounds__(128) void k_lstm_persist(
    const float* __restrict__ X,
    const float* __restrict__ Wih0, const float* __restrict__ Whh0,
    const float* __restrict__ bih0, const float* __restrict__ bhh0,
    const float* __restrict__ Wih1, const float* __restrict__ Whh1,
    const float* __restrict__ bih1, const float* __restrict__ bhh1,
    float* __restrict__ h0buf, float* __restrict__ h1buf,
    int* __restrict__ ctr) {
  extern __shared__ float sm[];
  float* wlds = sm;                       // up to 512*32 = 16384 floats
  int tid = threadIdx.x;
  int wv = tid >> 6, lane = tid & 63;
  float* aw   = sm + 16384 + wv*1152;     // per-wave 32k x stride-36 A chunk
  float* expb = sm + 16384 + 2*1152;      // 1024-float k-split export

  int layer = blockIdx.x & 1;
  int idx = blockIdx.x >> 1;
  int bg = idx >> 5, ut = idx & 31;
  int b0 = bg*32, u0 = ut*8;
  int K = layer ? 512 : 384;

  // one-time weight staging (k-major: wlds[k*32 + ug*4 + g])
  if (layer == 0) {
    for (int e = tid; e < 384*32; e += 128) {
      int k = e >> 5, ug_ = (e >> 2) & 7, g = e & 3;
      int row = g*256 + u0 + ug_;
      wlds[e] = (k < 128) ? Wih0[row*128 + k] : Whh0[row*256 + k - 128];
    }
  } else {
    for (int e = tid; e < 512*32; e += 128) {
      int k = e >> 5, ug_ = (e >> 2) & 7, g = e & 3;
      int row = g*256 + u0 + ug_;
      wlds[e] = (k < 256) ? Wih1[row*256 + k] : Whh1[row*256 + k - 256];
    }
  }

  int bl = lane & 31, q = lane >> 5;      // staging map
  int ug = lane & 7, bq = lane >> 3;      // compute map
  int uu = u0 + ug;
  float bsum[4] = {0.f, 0.f, 0.f, 0.f};
  if (wv == 0) {
    const float* bi = layer ? bih1 : bih0;
    const float* bh = layer ? bhh1 : bhh0;
#pragma unroll
    for (int g = 0; g < 4; ++g) bsum[g] = bi[g*256 + uu] + bh[g*256 + uu];
  }
  float c_reg[4] = {0.f, 0.f, 0.f, 0.f};
  int kbeg = wv * (K >> 1);
  int nch = K >> 6;                       // chunks of 32 per wave: 6 (L0) / 8 (L1)
  int* c0p = ctr + bg*80;
  int* c1p = ctr + 640 + bg*80;
  __syncthreads();

  for (int s = 0; s < 77; ++s) {
    // single-thread dependency poll (agent-scope relaxed loads + sleep backoff)
    if (tid == 0) {
      int w0t = -1, w1t = -1;
      if (layer == 0) { if (s >= 1) w0t = s-1; if (s >= 2) w1t = s-2; }
      else            { w0t = s;               if (s >= 1) w1t = s-1; }
      int guard = 0;
      if (w0t >= 0)
        while (__hip_atomic_load(c0p + w0t, __ATOMIC_RELAXED, __HIP_MEMORY_SCOPE_AGENT) < 32 &&
               ++guard < (1 << 20)) __builtin_amdgcn_s_sleep(2);
      guard = 0;
      if (w1t >= 0)
        while (__hip_atomic_load(c1p + w1t, __ATOMIC_RELAXED, __HIP_MEMORY_SCOPE_AGENT) < 32 &&
               ++guard < (1 << 20)) __builtin_amdgcn_s_sleep(2);
    }
    __syncthreads();

    const float* h0r  = h0buf + (s & 1)*65536;        // h0[s-1]
    const float* h0r2 = h0buf + ((s+1) & 1)*65536;    // h0[s]   (layer1 input)
    const float* h1r  = h1buf + (s & 1)*65536;        // h1[s-1]
    float* h0w = h0buf + ((s+1) & 1)*65536;
    float* h1w = h1buf + ((s+1) & 1)*65536;

    float acc[4][4] = {{0.f}};
    float hs[2][16];

#define LOADC(c) do {                                                              \
    int kc = kbeg + (c)*32;                                                        \
    if (layer == 0 && kc < 128) {                                                  \
      const float* ap = X + (size_t)s*32768 + (b0+bl)*128 + kc + q*16;             \
      _Pragma("unroll")                                                            \
      for (int i = 0; i < 4; ++i) {                                                \
        float4 v = *reinterpret_cast<const float4*>(ap + 4*i);                     \
        hs[(c)&1][4*i+0] = v.x; hs[(c)&1][4*i+1] = v.y;                            \
        hs[(c)&1][4*i+2] = v.z; hs[(c)&1][4*i+3] = v.w;                            \
      }                                                                            \
    } else {                                                                       \
      const float* hp; int off;                                                    \
      if (layer == 0)      { hp = h0r;  off = kc - 128; }                          \
      else if (kc < 256)   { hp = h0r2; off = kc; }                                \
      else                 { hp = h1r;  off = kc - 256; }                          \
      const double* ap = reinterpret_cast<const double*>(hp + (b0+bl)*256 + off + q*16); \
      _Pragma("unroll")                                                            \
      for (int i = 0; i < 8; ++i) {                                                \
        double d = __hip_atomic_load(ap + i, __ATOMIC_RELAXED, __HIP_MEMORY_SCOPE_AGENT); \
        float2 f2 = *reinterpret_cast<float2*>(&d);                                \
        hs[(c)&1][2*i+0] = f2.x; hs[(c)&1][2*i+1] = f2.y;                          \
      }                                                                            \
    }                                                                              \
  } while (0)

    LOADC(0);
    LOADC(1);
#pragma unroll
    for (int c = 0; c < 8; ++c) {
      if (c >= nch) break;
#pragma unroll
      for (int j = 0; j < 16; ++j)
        aw[(q*16 + j)*36 + bl] = hs[c & 1][j];
      if (c + 2 < nch) { LOADC(c + 2); }
#pragma unroll 8
      for (int kl = 0; kl < 32; ++kl) {
        float4 a4 = *reinterpret_cast<const float4*>(&aw[kl*36 + 4*bq]);
        float4 w4 = *reinterpret_cast<const float4*>(&wlds[(kbeg + c*32 + kl)*32 + 4*ug]);
        acc[0][0] += a4.x*w4.x; acc[0][1] += a4.x*w4.y; acc[0][2] += a4.x*w4.z; acc[0][3] += a4.x*w4.w;
        acc[1][0] += a4.y*w4.x; acc[1][1] += a4.y*w4.y; acc[1][2] += a4.y*w4.z; acc[1][3] += a4.y*w4.w;
        acc[2][0] += a4.z*w4.x; acc[2][1] += a4.z*w4.y; acc[2][2] += a4.z*w4.z; acc[2][3] += a4.z*w4.w;
        acc[3][0] += a4.w*w4.x; acc[3][1] += a4.w*w4.y; acc[3][2] += a4.w*w4.z; acc[3][3] += a4.w*w4.w;
      }
    }
#undef LOADC

    if (wv == 1) {
#pragma unroll
      for (int i = 0; i < 4; ++i)
#pragma unroll
        for (int g = 0; g < 4; ++g)
          expb[(i*4 + g)*64 + lane] = acc[i][g];
    }
    __syncthreads();
    if (wv == 0) {
      float* hw = layer ? h1w : h0w;
#pragma unroll
      for (int i = 0; i < 4; ++i) {
        float gi = acc[i][0] + expb[(i*4+0)*64 + lane] + bsum[0];
        float gf = acc[i][1] + expb[(i*4+1)*64 + lane] + bsum[1];
        float gg = acc[i][2] + expb[(i*4+2)*64 + lane] + bsum[2];
        float go = acc[i][3] + expb[(i*4+3)*64 + lane] + bsum[3];
        float si = 1.f/(1.f + expf(-gi));
        float sf = 1.f/(1.f + expf(-gf));
        float so = 1.f/(1.f + expf(-go));
        float tg = tanhf(gg);
        float cn = sf*c_reg[i] + si*tg;
        c_reg[i] = cn;
        float hv = so * tanhf(cn);
        __hip_atomic_store(hw + (b0 + 4*bq + i)*256 + uu, hv,
                           __ATOMIC_RELAXED, __HIP_MEMORY_SCOPE_AGENT);
      }
      __builtin_amdgcn_s_waitcnt(0);
      __asm__ __volatile__("" ::: "memory");
      if (lane == 0) atomicAdd((layer ? c1p : c0p) + s, 1);
    }
  }
}

// ---------------- FC: C = act(A @ W^T + b), M=256 ----------------
__global__ __launch_bounds__(256) void k_fc(const float* __restrict__ A,
    const float* __restrict__ W, const float* __restrict__ bias,
    float* __restrict__ Cout, int N, int K, int kshift, int dorelu) {
  __shared__ __align__(16) float sa[16*516];
  int m0 = blockIdx.y * 16;
  int n = blockIdx.x * 16 + (threadIdx.x & 15);
  int m = threadIdx.x >> 4;
  int stride = K + 4;
  for (int i = threadIdx.x; i < 16*K; i += 256) {
    int mm = i >> kshift;
    int kk = i - (mm << kshift);
    sa[mm*stride + kk] = A[(m0+mm)*K + kk];
  }
  __syncthreads();
  const float4* wr = reinterpret_cast<const float4*>(W + n*K);
  const float4* ar = reinterpret_cast<const float4*>(sa + m*stride);
  float acc = 0.f;
  int kq4 = K >> 2;
  for (int kq = 0; kq < kq4; ++kq) {
    float4 wv = wr[kq], av = ar[kq];
    acc += av.x*wv.x + av.y*wv.y + av.z*wv.z + av.w*wv.w;
  }
  acc += bias[n];
  if (dorelu) acc = fmaxf(acc, 0.f);
  Cout[(m0+m)*N + n] = acc;
}

extern "C" void kernel_launch(void* const* d_in, const int* in_sizes, int n_in,
                              void* d_out, int out_size, void* d_ws, size_t ws_size,
                              hipStream_t stream) {
  const float* x       = (const float*)d_in[0];
  const float* conv_w0 = (const float*)d_in[1];
  const float* conv_b0 = (const float*)d_in[2];
  const float* bn_g0   = (const float*)d_in[3];
  const float* bn_b0   = (const float*)d_in[4];
  const float* bn_m0   = (const float*)d_in[5];
  const float* bn_v0   = (const float*)d_in[6];
  const float* conv_w1 = (const float*)d_in[7];
  const float* conv_b1 = (const float*)d_in[8];
  const float* bn_g1   = (const float*)d_in[9];
  const float* bn_b1   = (const float*)d_in[10];
  const float* bn_m1   = (const float*)d_in[11];
  const float* bn_v1   = (const float*)d_in[12];
  const float* Wih0    = (const float*)d_in[13];
  const float* Whh0    = (const float*)d_in[14];
  const float* bih0    = (const float*)d_in[15];
  const float* bhh0    = (const float*)d_in[16];
  const float* Wih1    = (const float*)d_in[17];
  const float* Whh1    = (const float*)d_in[18];
  const float* bih1    = (const float*)d_in[19];
  const float* bhh1    = (const float*)d_in[20];
  const float* fc0_w   = (const float*)d_in[21];
  const float* fc0_b   = (const float*)d_in[22];
  const float* fc1_w   = (const float*)d_in[23];
  const float* fc1_b   = (const float*)d_in[24];
  const float* out_w   = (const float*)d_in[25];
  const float* out_b   = (const float*)d_in[26];
  float* ws = (float*)d_ws;
  float* out = (float*)d_out;

  static float h_consts[160];
  compute_consts(h_consts);
  hipMemcpyAsync(ws + OFF_CONST, h_consts, 160*sizeof(float), hipMemcpyHostToDevice, stream);
  hipMemsetAsync(ws + OFF_CTR, 0, 1280*sizeof(int), stream);
  hipMemsetAsync(ws + OFF_H0, 0, 131072*sizeof(float), stream);
  hipMemsetAsync(ws + OFF_H1, 0, 131072*sizeof(float), stream);

  k_sgconv0<<<dim3(3, BATCH), 256, 0, stream>>>(x, ws + OFF_CONST, conv_w0, conv_b0,
                                                bn_g0, bn_b0, bn_m0, bn_v0, ws + OFF_Y1);
  k_conv1_gemm<<<620, 256, 0, stream>>>(ws + OFF_Y1, conv_w1, conv_b1, ws + OFF_TMP);
  k_pool1<<<9856, 256, 0, stream>>>(ws + OFF_TMP, bn_g1, bn_b1, bn_m1, bn_v1, ws + OFF_X);

  // persistent LSTM: cooperative launch only for co-residency guarantee (no grid.sync inside)
  hipFuncSetAttribute(reinterpret_cast<const void*>(k_lstm_persist),
                      hipFuncAttributeMaxDynamicSharedMemorySize, 78848);
  const float* Xp = ws + OFF_X;
  float* h0p = ws + OFF_H0;
  float* h1p = ws + OFF_H1;
  int* ctrp = (int*)(ws + OFF_CTR);
  void* cargs[] = {(void*)&Xp, (void*)&Wih0, (void*)&Whh0, (void*)&bih0, (void*)&bhh0,
                   (void*)&Wih1, (void*)&Whh1, (void*)&bih1, (void*)&bhh1,
                   (void*)&h0p, (void*)&h1p, (void*)&ctrp};
  hipLaunchCooperativeKernel((void*)k_lstm_persist, dim3(512), dim3(128), cargs, 78848, stream);

  // final h1[76] lives at parity (76+1)&1 = 1
  k_fc<<<dim3(32, 16), 256, 0, stream>>>(ws + OFF_H1 + 65536, fc0_w, fc0_b, ws + OFF_Z0, 512, 256, 8, 1);
  k_fc<<<dim3(32, 16), 256, 0, stream>>>(ws + OFF_Z0, fc1_w, fc1_b, ws + OFF_Z1, 512, 512, 9, 1);
  k_fc<<<dim3(16, 16), 256, 0, stream>>>(ws + OFF_Z1, out_w, out_b, out, 256, 512, 9, 0);
}

// Round 6
// 1817.596 us; speedup vs baseline: 2.3654x; 1.0923x over previous
//
#include <hip/hip_runtime.h>
#include <math.h>

#define BATCH 256
#define LEN   10000
#define C0 64
#define P0 624
#define T1 155
#define P1 77

// ws offsets (in floats)
#define OFF_CONST 0
#define OFF_CTR   160           // 1280 ints (2 layers x 8 bg x 80 steps)
#define OFF_Y1    2560160       // 10,223,616 floats; DEAD after conv1 -> overlaid by h arrays
#define OFF_H0ALL 2560160       // 78 slots x 65536 (slot t+1 = h0[t], slot 0 = zeros)
#define OFF_H1ALL 7671968       // 78 slots x 65536
#define OFF_X     12783776
#define OFF_Z0    15700128
#define OFF_Z1    15831200
#define OFF_TMP   15962272

// ---------------- host-side savgol constants ----------------
static void invert4(const double A[4][4], double inv[4][4]) {
  double M[4][8];
  for (int i = 0; i < 4; ++i)
    for (int j = 0; j < 4; ++j) { M[i][j] = A[i][j]; M[i][j+4] = (i==j) ? 1.0 : 0.0; }
  for (int col = 0; col < 4; ++col) {
    int p = col;
    for (int r = col+1; r < 4; ++r) if (fabs(M[r][col]) > fabs(M[p][col])) p = r;
    if (p != col) for (int j = 0; j < 8; ++j) { double t = M[col][j]; M[col][j] = M[p][j]; M[p][j] = t; }
    double d = M[col][col];
    for (int j = 0; j < 8; ++j) M[col][j] /= d;
    for (int r = 0; r < 4; ++r) if (r != col) {
      double f = M[r][col];
      for (int j = 0; j < 8; ++j) M[r][j] -= f * M[col][j];
    }
  }
  for (int i = 0; i < 4; ++i) for (int j = 0; j < 4; ++j) inv[i][j] = M[i][j+4];
}

static void compute_consts(float* out) {
  {
    double V[11][4], A[4][4], inv[4][4];
    for (int w = 0; w < 11; ++w) { double t = (double)(w-5), pw = 1.0; for (int m = 0; m < 4; ++m) { V[w][m] = pw; pw *= t; } }
    for (int m = 0; m < 4; ++m) for (int n = 0; n < 4; ++n) { double s = 0; for (int w = 0; w < 11; ++w) s += V[w][m]*V[w][n]; A[m][n] = s; }
    invert4(A, inv);
    for (int w = 0; w < 11; ++w) { double s = 0; for (int m = 0; m < 4; ++m) s += inv[0][m]*V[w][m]; out[w] = (float)s; }
  }
  {
    double V[11][4], A[4][4], inv[4][4], pe[4][11];
    for (int w = 0; w < 11; ++w) { double t = (double)w, pw = 1.0; for (int m = 0; m < 4; ++m) { V[w][m] = pw; pw *= t; } }
    for (int m = 0; m < 4; ++m) for (int n = 0; n < 4; ++n) { double s = 0; for (int w = 0; w < 11; ++w) s += V[w][m]*V[w][n]; A[m][n] = s; }
    invert4(A, inv);
    for (int m = 0; m < 4; ++m) for (int w = 0; w < 11; ++w) { double s = 0; for (int n = 0; n < 4; ++n) s += inv[m][n]*V[w][n]; pe[m][w] = s; }
    for (int w = 0; w < 11; ++w) for (int k = 0; k < 5; ++k) {
      double s = 0, pk = 1.0;
      for (int m = 0; m < 4; ++m) { s += pe[m][w]*pk; pk *= (double)k; }
      out[16 + w*5 + k] = (float)s;
    }
    for (int w = 0; w < 11; ++w) for (int k = 0; k < 5; ++k) {
      double tv = (double)(6+k), s = 0, pk = 1.0;
      for (int m = 0; m < 4; ++m) { s += pe[m][w]*pk; pk *= tv; }
      out[80 + w*5 + k] = (float)s;
    }
  }
}

// ---------------- fused savgol + conv0 + relu + pool2 + bn ----------------
__global__ __launch_bounds__(256) void k_sgconv0(const float* __restrict__ x,
    const float* __restrict__ Cc,
    const float* __restrict__ w0, const float* __restrict__ cb0,
    const float* __restrict__ bg0, const float* __restrict__ bb0,
    const float* __restrict__ bm0, const float* __restrict__ bv0,
    float* __restrict__ y1) {
  __shared__ float sw[1024];
  __shared__ float s_sc[64], s_off[64], s_cb[64];
  int tid = threadIdx.x;
  for (int i = tid; i < 1024; i += 256) sw[i] = w0[i];
  if (tid < 64) {
    float sc = bg0[tid] * rsqrtf(bv0[tid] + 1e-5f);
    s_sc[tid] = sc;
    s_off[tid] = bb0[tid] - bm0[tid]*sc;
    s_cb[tid] = cb0[tid];
  }
  __syncthreads();
  int b = blockIdx.y;
  int uu = blockIdx.x*256 + tid;
  if (uu >= P0) return;
  const float* xb = x + b*LEN;
  float hC[11];
#pragma unroll
  for (int w = 0; w < 11; ++w) hC[w] = Cc[w];
  float iv[24];
  if (uu == 0) {
    float xx[32];
    const float4* p = reinterpret_cast<const float4*>(xb);
#pragma unroll
    for (int j = 0; j < 8; ++j) { float4 v = p[j]; xx[4*j]=v.x; xx[4*j+1]=v.y; xx[4*j+2]=v.z; xx[4*j+3]=v.w; }
#pragma unroll
    for (int j = 0; j < 24; ++j) {
      float s = 0.f;
      if (j < 5) {
        for (int w = 0; w < 11; ++w) s += xx[w] * Cc[16 + w*5 + j];
      } else {
        for (int w = 0; w < 11; ++w) s += xx[j-5+w] * hC[w];
      }
      iv[j] = s;
    }
  } else {
    float xx[40];
    const float4* p = reinterpret_cast<const float4*>(xb + 16*uu - 8);
#pragma unroll
    for (int j = 0; j < 10; ++j) { float4 v = p[j]; xx[4*j]=v.x; xx[4*j+1]=v.y; xx[4*j+2]=v.z; xx[4*j+3]=v.w; }
#pragma unroll
    for (int j = 0; j < 24; ++j) {
      float s = 0.f;
#pragma unroll
      for (int w = 0; w < 11; ++w) s += xx[j+3+w] * hC[w];
      iv[j] = s;
    }
  }
  int obase = b*(C0*P0) + uu;
  for (int oc = 0; oc < 64; ++oc) {
    float bias = s_cb[oc];
    float s0 = bias, s1 = bias;
#pragma unroll
    for (int k = 0; k < 16; ++k) {
      float wk = sw[oc*16 + k];
      s0 += iv[k]   * wk;
      s1 += iv[k+8] * wk;
    }
    float pm = fmaxf(fmaxf(s0, 0.f), fmaxf(s1, 0.f));
    y1[obase + oc*P0] = pm*s_sc[oc] + s_off[oc];
  }
}

// ---------------- conv1 as im2col GEMM ----------------
__global__ __launch_bounds__(256) void k_conv1_gemm(const float* __restrict__ y1,
    const float* __restrict__ w1, const float* __restrict__ cb1,
    float* __restrict__ tmp) {
  __shared__ __align__(16) float a_t[32*66];
  __shared__ __align__(16) float w_t[32*132];
  int m0 = blockIdx.x * 64;
  int tid = threadIdx.x;
  int sa_s = tid & 7, sa_r = tid >> 3;
  int un = tid & 31, mq = tid >> 5;
  int ybase[2];
#pragma unroll
  for (int i = 0; i < 2; ++i) {
    int m = m0 + sa_r + 32*i;
    int b = m / 155, t = m - b*155;
    ybase[i] = b*(C0*P0) + 4*t;
  }
  int ci_off = sa_s >> 1, kkq = (sa_s & 1) * 4;
  float4 av[2], wv[4];
  float acc[8][4] = {{0.f}};
  int swzw = sa_s << 2;

#define CONV1_PREFETCH(cidx) do {                                                   \
    int kc = (cidx) * 32;                                                           \
    int ci0 = kc >> 3;                                                              \
    av[0] = *reinterpret_cast<const float4*>(y1 + ybase[0] + (ci0 + ci_off)*P0 + kkq); \
    av[1] = *reinterpret_cast<const float4*>(y1 + ybase[1] + (ci0 + ci_off)*P0 + kkq); \
    _Pragma("unroll")                                                               \
    for (int i = 0; i < 4; ++i)                                                     \
      wv[i] = *reinterpret_cast<const float4*>(w1 + (sa_r + 32*i)*512 + kc + 4*sa_s); \
  } while (0)

  CONV1_PREFETCH(0);
  for (int cidx = 0; cidx < 16; ++cidx) {
    if (cidx) __syncthreads();
#pragma unroll
    for (int i = 0; i < 2; ++i) {
      int col = sa_r + 32*i;
      a_t[(4*sa_s+0)*66 + col] = av[i].x;
      a_t[(4*sa_s+1)*66 + col] = av[i].y;
      a_t[(4*sa_s+2)*66 + col] = av[i].z;
      a_t[(4*sa_s+3)*66 + col] = av[i].w;
    }
#pragma unroll
    for (int i = 0; i < 4; ++i) {
      int colw = (sa_r + 32*i) ^ swzw;
      w_t[(4*sa_s+0)*132 + colw] = wv[i].x;
      w_t[(4*sa_s+1)*132 + colw] = wv[i].y;
      w_t[(4*sa_s+2)*132 + colw] = wv[i].z;
      w_t[(4*sa_s+3)*132 + colw] = wv[i].w;
    }
    __syncthreads();
    if (cidx + 1 < 16) { CONV1_PREFETCH(cidx + 1); }
#pragma unroll
    for (int k = 0; k < 32; ++k) {
      float4 w4 = *reinterpret_cast<const float4*>(&w_t[k*132 + ((4*un) ^ ((k>>2)<<2))]);
      float2 a2[4];
#pragma unroll
      for (int i = 0; i < 4; ++i)
        a2[i] = *reinterpret_cast<const float2*>(&a_t[k*66 + 2*mq + 16*i]);
#pragma unroll
      for (int i = 0; i < 4; ++i) {
        acc[2*i+0][0] += a2[i].x*w4.x; acc[2*i+0][1] += a2[i].x*w4.y;
        acc[2*i+0][2] += a2[i].x*w4.z; acc[2*i+0][3] += a2[i].x*w4.w;
        acc[2*i+1][0] += a2[i].y*w4.x; acc[2*i+1][1] += a2[i].y*w4.y;
        acc[2*i+1][2] += a2[i].y*w4.z; acc[2*i+1][3] += a2[i].y*w4.w;
      }
    }
  }
#undef CONV1_PREFETCH
  float4 bias = *reinterpret_cast<const float4*>(cb1 + 4*un);
#pragma unroll
  for (int i = 0; i < 4; ++i)
#pragma unroll
    for (int jj = 0; jj < 2; ++jj) {
      int m = m0 + 2*mq + 16*i + jj;
      float4 o;
      o.x = acc[2*i+jj][0] + bias.x;
      o.y = acc[2*i+jj][1] + bias.y;
      o.z = acc[2*i+jj][2] + bias.z;
      o.w = acc[2*i+jj][3] + bias.w;
      *reinterpret_cast<float4*>(tmp + m*128 + 4*un) = o;
    }
}

// ---------------- relu + pool2 + bn: tmp -> X (77,256,128) ----------------
__global__ __launch_bounds__(256) void k_pool1(const float* __restrict__ tmp,
    const float* __restrict__ bg1, const float* __restrict__ bb1,
    const float* __restrict__ bm1, const float* __restrict__ bv1,
    float* __restrict__ X) {
  int idx = blockIdx.x*256 + threadIdx.x;
  int u  = idx >> 15;
  int rr = idx & 32767;
  int bb = rr >> 7;
  int oc = rr & 127;
  int base = (bb*155 + 2*u)*128 + oc;
  float t0 = tmp[base], t1 = tmp[base + 128];
  float pm = fmaxf(0.f, fmaxf(t0, t1));
  float sc = bg1[oc] * rsqrtf(bv1[oc] + 1e-5f);
  X[idx] = pm*sc + (bb1[oc] - bm1[oc]*sc);
}

// ---------------- persistent LSTM: per-step fresh h buffers + plain cached reads ----------------
// 512 blocks x 128 threads (2/CU). Block = (layer, bg = batch/32, ut = units/8).
// h[t] lives in its own 65536-float slot (t+1); slot 0 = zeros. Producers: sc1 write-through
// stores + device atomicAdd signal. Consumers: counter-gated PLAIN float4 loads (L2-cached,
// coalesced; first touch per XCD fills from L3 which holds the fresh write-through data).
__global__ __launch_bounds__(128) void k_lstm_persist(
    const float* __restrict__ X,
    const float* __restrict__ Wih0, const float* __restrict__ Whh0,
    const float* __restrict__ bih0, const float* __restrict__ bhh0,
    const float* __restrict__ Wih1, const float* __restrict__ Whh1,
    const float* __restrict__ bih1, const float* __restrict__ bhh1,
    float* __restrict__ h0a, float* __restrict__ h1a,
    int* __restrict__ ctr) {
  extern __shared__ float sm[];
  float* wlds = sm;                       // up to 512*32 = 16384 floats
  int tid = threadIdx.x;
  int wv = tid >> 6, lane = tid & 63;
  float* aw   = sm + 16384 + wv*1152;     // per-wave 32k x stride-36 A chunk
  float* expb = sm + 16384 + 2*1152;      // 1024-float k-split export

  int layer = blockIdx.x & 1;
  int idx = blockIdx.x >> 1;
  int bg = idx >> 5, ut = idx & 31;
  int b0 = bg*32, u0 = ut*8;
  int K = layer ? 512 : 384;

  // one-time weight staging (k-major: wlds[k*32 + ug*4 + g])
  if (layer == 0) {
    for (int e = tid; e < 384*32; e += 128) {
      int k = e >> 5, ug_ = (e >> 2) & 7, g = e & 3;
      int row = g*256 + u0 + ug_;
      wlds[e] = (k < 128) ? Wih0[row*128 + k] : Whh0[row*256 + k - 128];
    }
  } else {
    for (int e = tid; e < 512*32; e += 128) {
      int k = e >> 5, ug_ = (e >> 2) & 7, g = e & 3;
      int row = g*256 + u0 + ug_;
      wlds[e] = (k < 256) ? Wih1[row*256 + k] : Whh1[row*256 + k - 256];
    }
  }

  int bl = lane & 31, q = lane >> 5;      // staging map
  int ug = lane & 7, bq = lane >> 3;      // compute map
  int uu = u0 + ug;
  float bsum[4] = {0.f, 0.f, 0.f, 0.f};
  if (wv == 0) {
    const float* bi = layer ? bih1 : bih0;
    const float* bh = layer ? bhh1 : bhh0;
#pragma unroll
    for (int g = 0; g < 4; ++g) bsum[g] = bi[g*256 + uu] + bh[g*256 + uu];
  }
  float c_reg[4] = {0.f, 0.f, 0.f, 0.f};
  int kbeg = wv * (K >> 1);
  int nch = K >> 6;                       // chunks of 32 per wave: 6 (L0) / 8 (L1)
  int* c0p = ctr + bg*80;
  int* c1p = ctr + 640 + bg*80;
  __syncthreads();

  for (int s = 0; s < 77; ++s) {
    // single-thread dependency poll (agent-scope relaxed loads + sleep backoff)
    if (tid == 0) {
      int guard = 0;
      if (layer == 0) {
        if (s >= 1)
          while (__hip_atomic_load(c0p + s - 1, __ATOMIC_RELAXED, __HIP_MEMORY_SCOPE_AGENT) < 32 &&
                 ++guard < (1 << 20)) __builtin_amdgcn_s_sleep(1);
      } else {
        while (__hip_atomic_load(c0p + s, __ATOMIC_RELAXED, __HIP_MEMORY_SCOPE_AGENT) < 32 &&
               ++guard < (1 << 20)) __builtin_amdgcn_s_sleep(1);
        guard = 0;
        if (s >= 1)
          while (__hip_atomic_load(c1p + s - 1, __ATOMIC_RELAXED, __HIP_MEMORY_SCOPE_AGENT) < 32 &&
                 ++guard < (1 << 20)) __builtin_amdgcn_s_sleep(1);
      }
    }
    __syncthreads();

    float acc[4][4] = {{0.f}};
    float hs[2][16];

    // plain cached loads: slot addresses are unique per step (no stale lines possible)
#define LOADC(c) do {                                                              \
    int kc = kbeg + (c)*32;                                                        \
    const float* ap;                                                               \
    if (layer == 0) {                                                              \
      if (kc < 128) ap = X   + (size_t)s*32768     + (b0+bl)*128 + kc         + q*16; \
      else          ap = h0a + (size_t)s*65536     + (b0+bl)*256 + (kc - 128) + q*16; \
    } else {                                                                       \
      if (kc < 256) ap = h0a + (size_t)(s+1)*65536 + (b0+bl)*256 + kc         + q*16; \
      else          ap = h1a + (size_t)s*65536     + (b0+bl)*256 + (kc - 256) + q*16; \
    }                                                                              \
    _Pragma("unroll")                                                              \
    for (int i = 0; i < 4; ++i) {                                                  \
      float4 v = *reinterpret_cast<const float4*>(ap + 4*i);                       \
      hs[(c)&1][4*i+0] = v.x; hs[(c)&1][4*i+1] = v.y;                              \
      hs[(c)&1][4*i+2] = v.z; hs[(c)&1][4*i+3] = v.w;                              \
    }                                                                              \
  } while (0)

    LOADC(0);
    LOADC(1);
#pragma unroll
    for (int c = 0; c < 8; ++c) {
      if (c >= nch) break;
#pragma unroll
      for (int j = 0; j < 16; ++j)
        aw[(q*16 + j)*36 + bl] = hs[c & 1][j];
      if (c + 2 < nch) { LOADC(c + 2); }
#pragma unroll 8
      for (int kl = 0; kl < 32; ++kl) {
        float4 a4 = *reinterpret_cast<const float4*>(&aw[kl*36 + 4*bq]);
        float4 w4 = *reinterpret_cast<const float4*>(&wlds[(kbeg + c*32 + kl)*32 + 4*ug]);
        acc[0][0] += a4.x*w4.x; acc[0][1] += a4.x*w4.y; acc[0][2] += a4.x*w4.z; acc[0][3] += a4.x*w4.w;
        acc[1][0] += a4.y*w4.x; acc[1][1] += a4.y*w4.y; acc[1][2] += a4.y*w4.z; acc[1][3] += a4.y*w4.w;
        acc[2][0] += a4.z*w4.x; acc[2][1] += a4.z*w4.y; acc[2][2] += a4.z*w4.z; acc[2][3] += a4.z*w4.w;
        acc[3][0] += a4.w*w4.x; acc[3][1] += a4.w*w4.y; acc[3][2] += a4.w*w4.z; acc[3][3] += a4.w*w4.w;
      }
    }
#undef LOADC

    if (wv == 1) {
#pragma unroll
      for (int i = 0; i < 4; ++i)
#pragma unroll
        for (int g = 0; g < 4; ++g)
          expb[(i*4 + g)*64 + lane] = acc[i][g];
    }
    __syncthreads();
    if (wv == 0) {
      float* hw = (layer ? h1a : h0a) + (size_t)(s+1)*65536;
#pragma unroll
      for (int i = 0; i < 4; ++i) {
        float gi = acc[i][0] + expb[(i*4+0)*64 + lane] + bsum[0];
        float gf = acc[i][1] + expb[(i*4+1)*64 + lane] + bsum[1];
        float gg = acc[i][2] + expb[(i*4+2)*64 + lane] + bsum[2];
        float go = acc[i][3] + expb[(i*4+3)*64 + lane] + bsum[3];
        float si = 1.f/(1.f + expf(-gi));
        float sf = 1.f/(1.f + expf(-gf));
        float so = 1.f/(1.f + expf(-go));
        float tg = tanhf(gg);
        float cn = sf*c_reg[i] + si*tg;
        c_reg[i] = cn;
        float hv = so * tanhf(cn);
        // write-through to the coherence point (L3) so cross-XCD consumers' L2 fills are fresh
        __hip_atomic_store(hw + (b0 + 4*bq + i)*256 + uu, hv,
                           __ATOMIC_RELAXED, __HIP_MEMORY_SCOPE_AGENT);
      }
      __builtin_amdgcn_s_waitcnt(0);
      __asm__ __volatile__("" ::: "memory");
      if (lane == 0) atomicAdd((layer ? c1p : c0p) + s, 1);
    }
  }
}

// ---------------- FC: C = act(A @ W^T + b), M=256 ----------------
__global__ __launch_bounds__(256) void k_fc(const float* __restrict__ A,
    const float* __restrict__ W, const float* __restrict__ bias,
    float* __restrict__ Cout, int N, int K, int kshift, int dorelu) {
  __shared__ __align__(16) float sa[16*516];
  int m0 = blockIdx.y * 16;
  int n = blockIdx.x * 16 + (threadIdx.x & 15);
  int m = threadIdx.x >> 4;
  int stride = K + 4;
  for (int i = threadIdx.x; i < 16*K; i += 256) {
    int mm = i >> kshift;
    int kk = i - (mm << kshift);
    sa[mm*stride + kk] = A[(m0+mm)*K + kk];
  }
  __syncthreads();
  const float4* wr = reinterpret_cast<const float4*>(W + n*K);
  const float4* ar = reinterpret_cast<const float4*>(sa + m*stride);
  float acc = 0.f;
  int kq4 = K >> 2;
  for (int kq = 0; kq < kq4; ++kq) {
    float4 wv = wr[kq], av = ar[kq];
    acc += av.x*wv.x + av.y*wv.y + av.z*wv.z + av.w*wv.w;
  }
  acc += bias[n];
  if (dorelu) acc = fmaxf(acc, 0.f);
  Cout[(m0+m)*N + n] = acc;
}

extern "C" void kernel_launch(void* const* d_in, const int* in_sizes, int n_in,
                              void* d_out, int out_size, void* d_ws, size_t ws_size,
                              hipStream_t stream) {
  const float* x       = (const float*)d_in[0];
  const float* conv_w0 = (const float*)d_in[1];
  const float* conv_b0 = (const float*)d_in[2];
  const float* bn_g0   = (const float*)d_in[3];
  const float* bn_b0   = (const float*)d_in[4];
  const float* bn_m0   = (const float*)d_in[5];
  const float* bn_v0   = (const float*)d_in[6];
  const float* conv_w1 = (const float*)d_in[7];
  const float* conv_b1 = (const float*)d_in[8];
  const float* bn_g1   = (const float*)d_in[9];
  const float* bn_b1   = (const float*)d_in[10];
  const float* bn_m1   = (const float*)d_in[11];
  const float* bn_v1   = (const float*)d_in[12];
  const float* Wih0    = (const float*)d_in[13];
  const float* Whh0    = (const float*)d_in[14];
  const float* bih0    = (const float*)d_in[15];
  const float* bhh0    = (const float*)d_in[16];
  const float* Wih1    = (const float*)d_in[17];
  const float* Whh1    = (const float*)d_in[18];
  const float* bih1    = (const float*)d_in[19];
  const float* bhh1    = (const float*)d_in[20];
  const float* fc0_w   = (const float*)d_in[21];
  const float* fc0_b   = (const float*)d_in[22];
  const float* fc1_w   = (const float*)d_in[23];
  const float* fc1_b   = (const float*)d_in[24];
  const float* out_w   = (const float*)d_in[25];
  const float* out_b   = (const float*)d_in[26];
  float* ws = (float*)d_ws;
  float* out = (float*)d_out;

  static float h_consts[160];
  compute_consts(h_consts);
  hipMemcpyAsync(ws + OFF_CONST, h_consts, 160*sizeof(float), hipMemcpyHostToDevice, stream);
  hipMemsetAsync(ws + OFF_CTR, 0, 1280*sizeof(int), stream);

  k_sgconv0<<<dim3(3, BATCH), 256, 0, stream>>>(x, ws + OFF_CONST, conv_w0, conv_b0,
                                                bn_g0, bn_b0, bn_m0, bn_v0, ws + OFF_Y1);
  k_conv1_gemm<<<620, 256, 0, stream>>>(ws + OFF_Y1, conv_w1, conv_b1, ws + OFF_TMP);
  // Y1 region is dead now -> zero the h[-1] slots that overlay it
  hipMemsetAsync(ws + OFF_H0ALL, 0, 65536*sizeof(float), stream);
  hipMemsetAsync(ws + OFF_H1ALL, 0, 65536*sizeof(float), stream);
  k_pool1<<<9856, 256, 0, stream>>>(ws + OFF_TMP, bn_g1, bn_b1, bn_m1, bn_v1, ws + OFF_X);

  // persistent LSTM: cooperative launch only for co-residency guarantee (no grid.sync inside)
  hipFuncSetAttribute(reinterpret_cast<const void*>(k_lstm_persist),
                      hipFuncAttributeMaxDynamicSharedMemorySize, 78848);
  const float* Xp = ws + OFF_X;
  float* h0p = ws + OFF_H0ALL;
  float* h1p = ws + OFF_H1ALL;
  int* ctrp = (int*)(ws + OFF_CTR);
  void* cargs[] = {(void*)&Xp, (void*)&Wih0, (void*)&Whh0, (void*)&bih0, (void*)&bhh0,
                   (void*)&Wih1, (void*)&Whh1, (void*)&bih1, (void*)&bhh1,
                   (void*)&h0p, (void*)&h1p, (void*)&ctrp};
  hipLaunchCooperativeKernel((void*)k_lstm_persist, dim3(512), dim3(128), cargs, 78848, stream);

  // final h1[76] = slot 77 of h1a
  k_fc<<<dim3(32, 16), 256, 0, stream>>>(ws + OFF_H1ALL + (size_t)77*65536, fc0_w, fc0_b, ws + OFF_Z0, 512, 256, 8, 1);
  k_fc<<<dim3(32, 16), 256, 0, stream>>>(ws + OFF_Z0, fc1_w, fc1_b, ws + OFF_Z1, 512, 512, 9, 1);
  k_fc<<<dim3(16, 16), 256, 0, stream>>>(ws + OFF_Z1, out_w, out_b, out, 256, 512, 9, 0);
}